// Round 10
// baseline (946.543 us; speedup 1.0000x reference)
//
#include <hip/hip_runtime.h>
#include <hip/hip_cooperative_groups.h>

namespace cg = cooperative_groups;

#define N_NODES 50000
#define N_EDGES 800000
static constexpr float EPS = 1e-5f;
static constexpr int SCAN_NB  = (N_NODES + 255) / 256;   // 196
static constexpr int GEMM_NB  = (N_NODES + 63) / 64;     // 782
static constexpr int FILL_NB  = (N_EDGES + 1023) / 1024; // 782 (4 edges/thread)
static constexpr int AGG128_NB = N_NODES / 16;           // 3125
static constexpr int AGG64_NB  = (N_NODES + 31) / 32;    // 1563
static constexpr int STATS_NB  = 256;
static constexpr int WCONV_N   = 40960;

using bf16x8 = __attribute__((ext_vector_type(8))) short;  // 8 bf16 (4 VGPRs)
using f32x4  = __attribute__((ext_vector_type(4))) float;

// ---- bf16 helpers (raw-bit, RNE) ----
static __device__ __forceinline__ unsigned short f2bf(float f) {
    unsigned int u = __float_as_uint(f);
    return (unsigned short)((u + 0x7FFFu + ((u >> 16) & 1u)) >> 16);
}
static __device__ __forceinline__ float blo(unsigned int w) { return __uint_as_float(w << 16); }
static __device__ __forceinline__ float bhi(unsigned int w) { return __uint_as_float(w & 0xffff0000u); }

struct MegaParams {
    const int* ei;
    const float* x;
    const float* W1; const float* W2; const float* W3;
    const float* b1; const float* g1; const float* bt1;
    const float* b2; const float* g2; const float* bt2;
    const float* b3;
    float* out;
    int* deg; int* excl; int* partials; int* rowptr; int* rank; int* esrc;
    float* inv_sqrt; float* stats1; float* stats2;
    unsigned short* Wf1; unsigned short* Wf2; unsigned short* Wf3;
    unsigned short* h1; unsigned short* h2; unsigned short* h3;
    unsigned short* agg1; unsigned short* agg2;
    int zero16;          // 16B chunks to zero starting at deg
};

// ---------------------------------------------------------------------------
// MFMA GEMM tile: H(bf16) = act(A) @ W; act = BN+ReLU if BN. Loop-safe (LDS
// reuse protected by trailing __syncthreads).
// ---------------------------------------------------------------------------
template <int NCOL, bool BN, bool ABF16>
static __device__ __forceinline__ void gemm_body(
    int row0, int t,
    const void* __restrict__ Ap, const unsigned short* __restrict__ Wf,
    const float* __restrict__ stats,
    const float* __restrict__ gamma, const float* __restrict__ beta,
    unsigned short* __restrict__ H,
    unsigned short* As, float* sc_s, float* sh_s) {
    if (BN) {
        if (t < 128) {
            float s  = stats[t];
            float sq = stats[128 + t];
            float mean = s * (1.0f / N_NODES);
            float var  = sq * (1.0f / N_NODES) - mean * mean;
            float sc = gamma[t] * rsqrtf(var + EPS);
            sc_s[t] = sc;
            sh_s[t] = beta[t] - mean * sc;
        }
        __syncthreads();
    }

#pragma unroll
    for (int i = 0; i < 4; i++) {
        int q = i * 256 + t;
        int row = q >> 4;
        int c8  = (q & 15) * 8;
        int grow = row0 + row;
        float v[8];
        if (grow < N_NODES) {
            if (ABF16) {
                uint4 p = *(const uint4*)((const unsigned short*)Ap + (size_t)grow * 128 + c8);
                v[0] = blo(p.x); v[1] = bhi(p.x); v[2] = blo(p.y); v[3] = bhi(p.y);
                v[4] = blo(p.z); v[5] = bhi(p.z); v[6] = blo(p.w); v[7] = bhi(p.w);
            } else {
                const float* Af = (const float*)Ap + (size_t)grow * 128 + c8;
                float4 f0 = *(const float4*)Af;
                float4 f1 = *(const float4*)(Af + 4);
                v[0] = f0.x; v[1] = f0.y; v[2] = f0.z; v[3] = f0.w;
                v[4] = f1.x; v[5] = f1.y; v[6] = f1.z; v[7] = f1.w;
            }
        } else {
#pragma unroll
            for (int j = 0; j < 8; j++) v[j] = 0.f;
        }
        if (BN) {
#pragma unroll
            for (int j = 0; j < 8; j++)
                v[j] = fmaxf(fmaf(v[j], sc_s[c8 + j], sh_s[c8 + j]), 0.f);
        }
        uint4 pk;
        pk.x = (unsigned)f2bf(v[0]) | ((unsigned)f2bf(v[1]) << 16);
        pk.y = (unsigned)f2bf(v[2]) | ((unsigned)f2bf(v[3]) << 16);
        pk.z = (unsigned)f2bf(v[4]) | ((unsigned)f2bf(v[5]) << 16);
        pk.w = (unsigned)f2bf(v[6]) | ((unsigned)f2bf(v[7]) << 16);
        *(uint4*)&As[row * 136 + c8] = pk;
    }
    __syncthreads();

    const int wv = t >> 6;
    const int l  = t & 63;
    const int m  = l & 15;
    const int kq = l >> 4;

    bf16x8 afrag[4];
    const unsigned short* arow = &As[(wv * 16 + m) * 136 + kq * 8];
#pragma unroll
    for (int s = 0; s < 4; s++)
        afrag[s] = *(const bf16x8*)(arow + s * 32);

    constexpr int NT = NCOL / 16;
#pragma unroll
    for (int tn = 0; tn < NT; tn++) {
        f32x4 acc = {0.f, 0.f, 0.f, 0.f};
#pragma unroll
        for (int s = 0; s < 4; s++) {
            bf16x8 b = *(const bf16x8*)&Wf[(size_t)((tn * 4 + s) * 64 + l) * 8];
            acc = __builtin_amdgcn_mfma_f32_16x16x32_bf16(afrag[s], b, acc, 0, 0, 0);
        }
        int col = tn * 16 + m;
#pragma unroll
        for (int r = 0; r < 4; r++) {
            int row = row0 + wv * 16 + kq * 4 + r;
            if (row < N_NODES) H[(size_t)row * NCOL + col] = f2bf(acc[r]);
        }
    }
    __syncthreads();   // protect As for next grid-stride iteration
}

// ---------------------------------------------------------------------------
// CSR gather-aggregate item (one group of nodes), 16 B/lane, 4-wide unroll
// ---------------------------------------------------------------------------
template <int F, bool OUTBF>
static __device__ __forceinline__ void agg_item(
    int w, int t, const int* __restrict__ rowptr, const int* __restrict__ esrc,
    const float* __restrict__ inv_sqrt, const unsigned short* __restrict__ H,
    const float* __restrict__ bias, void* __restrict__ OUT) {
    constexpr int LPN = F / 8;
    constexpr int NPB = 256 / LPN;
    const int node = w * NPB + t / LPN;
    const int lane = t % LPN;
    if (node >= N_NODES) return;

    const uint4* __restrict__ Hv = (const uint4*)H;
    const int beg = rowptr[node];
    const int end = rowptr[node + 1];
    const float rsn = inv_sqrt[node];

    float acc[8];
#pragma unroll
    for (int i = 0; i < 8; i++) acc[i] = 0.f;

#define ACC8(P, C)                                                     \
    acc[0] = fmaf(blo((P).x), (C), acc[0]);                            \
    acc[1] = fmaf(bhi((P).x), (C), acc[1]);                            \
    acc[2] = fmaf(blo((P).y), (C), acc[2]);                            \
    acc[3] = fmaf(bhi((P).y), (C), acc[3]);                            \
    acc[4] = fmaf(blo((P).z), (C), acc[4]);                            \
    acc[5] = fmaf(bhi((P).z), (C), acc[5]);                            \
    acc[6] = fmaf(blo((P).w), (C), acc[6]);                            \
    acc[7] = fmaf(bhi((P).w), (C), acc[7]);

    int j = beg;
    for (; j + 3 < end; j += 4) {
        int s0 = esrc[j], s1 = esrc[j + 1], s2 = esrc[j + 2], s3 = esrc[j + 3];
        uint4 p0 = Hv[(size_t)s0 * LPN + lane];
        uint4 p1 = Hv[(size_t)s1 * LPN + lane];
        uint4 p2 = Hv[(size_t)s2 * LPN + lane];
        uint4 p3 = Hv[(size_t)s3 * LPN + lane];
        float c0 = inv_sqrt[s0] * rsn, c1 = inv_sqrt[s1] * rsn;
        float c2 = inv_sqrt[s2] * rsn, c3 = inv_sqrt[s3] * rsn;
        ACC8(p0, c0) ACC8(p1, c1) ACC8(p2, c2) ACC8(p3, c3)
    }
    for (; j < end; j++) {
        int s0 = esrc[j];
        float c0 = inv_sqrt[s0] * rsn;
        uint4 p0 = Hv[(size_t)s0 * LPN + lane];
        ACC8(p0, c0)
    }
#undef ACC8

    uint4 ps = Hv[(size_t)node * LPN + lane];
    float idv = rsn * rsn;
    float4 b0 = ((const float4*)bias)[lane * 2];
    float4 b1 = ((const float4*)bias)[lane * 2 + 1];
    acc[0] = fmaf(blo(ps.x), idv, acc[0]) + b0.x;
    acc[1] = fmaf(bhi(ps.x), idv, acc[1]) + b0.y;
    acc[2] = fmaf(blo(ps.y), idv, acc[2]) + b0.z;
    acc[3] = fmaf(bhi(ps.y), idv, acc[3]) + b0.w;
    acc[4] = fmaf(blo(ps.z), idv, acc[4]) + b1.x;
    acc[5] = fmaf(bhi(ps.z), idv, acc[5]) + b1.y;
    acc[6] = fmaf(blo(ps.w), idv, acc[6]) + b1.z;
    acc[7] = fmaf(bhi(ps.w), idv, acc[7]) + b1.w;

    if (OUTBF) {
        uint4 pk;
        pk.x = (unsigned)f2bf(acc[0]) | ((unsigned)f2bf(acc[1]) << 16);
        pk.y = (unsigned)f2bf(acc[2]) | ((unsigned)f2bf(acc[3]) << 16);
        pk.z = (unsigned)f2bf(acc[4]) | ((unsigned)f2bf(acc[5]) << 16);
        pk.w = (unsigned)f2bf(acc[6]) | ((unsigned)f2bf(acc[7]) << 16);
        ((uint4*)OUT)[(size_t)node * LPN + lane] = pk;
    } else {
        float4* o = (float4*)OUT + ((size_t)node * LPN + lane) * 2;
        o[0] = make_float4(acc[0], acc[1], acc[2], acc[3]);
        o[1] = make_float4(acc[4], acc[5], acc[6], acc[7]);
    }
}

// ---------------------------------------------------------------------------
// column-stats item over bf16 A[N,128] (STATS_NB work items)
// ---------------------------------------------------------------------------
static __device__ __forceinline__ void stats_item(
    int w, int t, const unsigned short* __restrict__ A, float* __restrict__ stats,
    float4 (*red)[8][32]) {
    const int c4 = t & 31;
    const int rr = t >> 5;
    float4 sum = make_float4(0.f, 0.f, 0.f, 0.f);
    float4 sq  = make_float4(0.f, 0.f, 0.f, 0.f);
    for (int row = w * 8 + rr; row < N_NODES; row += STATS_NB * 8) {
        uint2 p = *(const uint2*)&A[(size_t)row * 128 + c4 * 4];
        float vx = blo(p.x), vy = bhi(p.x), vz = blo(p.y), vw = bhi(p.y);
        sum.x += vx; sum.y += vy; sum.z += vz; sum.w += vw;
        sq.x += vx * vx; sq.y += vy * vy; sq.z += vz * vz; sq.w += vw * vw;
    }
    red[0][rr][c4] = sum;
    red[1][rr][c4] = sq;
    __syncthreads();
    if (t < 32) {
        float4 s = make_float4(0.f, 0.f, 0.f, 0.f);
        float4 q = make_float4(0.f, 0.f, 0.f, 0.f);
#pragma unroll
        for (int i = 0; i < 8; i++) {
            float4 a = red[0][i][t];
            float4 b = red[1][i][t];
            s.x += a.x; s.y += a.y; s.z += a.z; s.w += a.w;
            q.x += b.x; q.y += b.y; q.z += b.z; q.w += b.w;
        }
        int c = t * 4;
        atomicAdd(&stats[c + 0], s.x); atomicAdd(&stats[c + 1], s.y);
        atomicAdd(&stats[c + 2], s.z); atomicAdd(&stats[c + 3], s.w);
        atomicAdd(&stats[128 + c + 0], q.x); atomicAdd(&stats[128 + c + 1], q.y);
        atomicAdd(&stats[128 + c + 2], q.z); atomicAdd(&stats[128 + c + 3], q.w);
    }
    __syncthreads();
}

// ---------------------------------------------------------------------------
// THE mega kernel: whole 3-layer GCN in one cooperative launch.
// All phases grid-stride; grid.sync() between dependent phases.
// ---------------------------------------------------------------------------
__global__ __launch_bounds__(256, 4) void k_mega(MegaParams p) {
    cg::grid_group grid = cg::this_grid();
    const int t   = threadIdx.x;
    const int bid = blockIdx.x;
    const int nb  = gridDim.x;
    const int gtid = bid * 256 + t;
    const int gsz  = nb * 256;

    __shared__ unsigned short As[64 * 136];
    __shared__ float sc_s[128], sh_s[128];
    __shared__ int shi[256];
    __shared__ float4 red[2][8][32];

    // -- phase 0: zero deg/stats region + pack all weights to fragment order
    {
        int4* z = (int4*)p.deg;
        for (int i = gtid; i < p.zero16; i += gsz) z[i] = make_int4(0, 0, 0, 0);
        for (int gid = gtid; gid < WCONV_N; gid += gsz) {
            const float* W; unsigned short* Wf; int NCOL, idx;
            if (gid < 16384)      { W = p.W1; Wf = p.Wf1; NCOL = 128; idx = gid; }
            else if (gid < 32768) { W = p.W2; Wf = p.Wf2; NCOL = 128; idx = gid - 16384; }
            else                  { W = p.W3; Wf = p.Wf3; NCOL = 64;  idx = gid - 32768; }
            int j  = idx & 7;
            int l  = (idx >> 3) & 63;
            int s  = (idx >> 9) & 3;
            int tn = idx >> 11;
            int n = tn * 16 + (l & 15);
            int k = s * 32 + (l >> 4) * 8 + j;
            Wf[idx] = f2bf(W[k * NCOL + n]);
        }
    }
    grid.sync();

    // -- phase 1: histogram+rank (atomic pipe) || layer-1 GEMM (MFMA pipe)
    for (int w = bid; w < FILL_NB + GEMM_NB; w += nb) {
        if (w < FILL_NB) {
            int e0 = (w * 256 + t) * 4;
            if (e0 < N_EDGES) {
                int4 d4 = *(const int4*)&p.ei[N_EDGES + e0];
                int4 r;
                r.x = atomicAdd(&p.deg[d4.x], 1);
                r.y = atomicAdd(&p.deg[d4.y], 1);
                r.z = atomicAdd(&p.deg[d4.z], 1);
                r.w = atomicAdd(&p.deg[d4.w], 1);
                *(int4*)&p.rank[e0] = r;
            }
        } else {
            gemm_body<128, false, false>((w - FILL_NB) * 64, t, p.x, p.Wf1,
                                         nullptr, nullptr, nullptr, p.h1,
                                         As, sc_s, sh_s);
        }
    }
    grid.sync();

    // -- phase 2: scan stage 1 (block-local excl scan + partials + inv_sqrt)
    for (int w = bid; w < SCAN_NB; w += nb) {
        int i = w * 256 + t;
        int v = (i < N_NODES) ? p.deg[i] : 0;
        if (i < N_NODES) p.inv_sqrt[i] = rsqrtf((float)v + 1.0f);
        shi[t] = v;
        __syncthreads();
        for (int off = 1; off < 256; off <<= 1) {
            int u = (t >= off) ? shi[t - off] : 0;
            __syncthreads();
            shi[t] += u;
            __syncthreads();
        }
        if (i < N_NODES) p.excl[i] = shi[t] - v;
        if (t == 255) p.partials[w] = shi[t];
        __syncthreads();
    }
    grid.sync();

    // -- phase 3: scan stages 2+3 (redundant partial-scan per item -> rowptr)
    for (int w = bid; w < SCAN_NB; w += nb) {
        int v = (t < SCAN_NB) ? p.partials[t] : 0;
        shi[t] = v;
        __syncthreads();
        for (int off = 1; off < 256; off <<= 1) {
            int u = (t >= off) ? shi[t - off] : 0;
            __syncthreads();
            shi[t] += u;
            __syncthreads();
        }
        int base = shi[w] - p.partials[w];      // exclusive prefix of item w
        int i = w * 256 + t;
        if (i < N_NODES) p.rowptr[i] = p.excl[i] + base;
        if (i == 0) p.rowptr[N_NODES] = N_EDGES;
        __syncthreads();
    }
    grid.sync();

    // -- phase 4: CSR fill (atomic-free: pos = rowptr[dst] + rank)
    for (int w = bid; w < FILL_NB; w += nb) {
        int e0 = (w * 256 + t) * 4;
        if (e0 < N_EDGES) {
            int4 s4 = *(const int4*)&p.ei[e0];
            int4 d4 = *(const int4*)&p.ei[N_EDGES + e0];
            int4 r4 = *(const int4*)&p.rank[e0];
            p.esrc[p.rowptr[d4.x] + r4.x] = s4.x;
            p.esrc[p.rowptr[d4.y] + r4.y] = s4.y;
            p.esrc[p.rowptr[d4.z] + r4.z] = s4.z;
            p.esrc[p.rowptr[d4.w] + r4.w] = s4.w;
        }
    }
    grid.sync();

    // -- phase 5: layer-1 aggregate (h1 -> agg1 bf16, +b1)
    for (int w = bid; w < AGG128_NB; w += nb)
        agg_item<128, true>(w, t, p.rowptr, p.esrc, p.inv_sqrt, p.h1, p.b1, p.agg1);
    grid.sync();

    // -- phase 6: stats over agg1
    for (int w = bid; w < STATS_NB; w += nb)
        stats_item(w, t, p.agg1, p.stats1, red);
    grid.sync();

    // -- phase 7: layer-2 GEMM (BN(g1,bt1)+ReLU fused)
    for (int w = bid; w < GEMM_NB; w += nb)
        gemm_body<128, true, true>(w * 64, t, p.agg1, p.Wf2, p.stats1,
                                   p.g1, p.bt1, p.h2, As, sc_s, sh_s);
    grid.sync();

    // -- phase 8: layer-2 aggregate
    for (int w = bid; w < AGG128_NB; w += nb)
        agg_item<128, true>(w, t, p.rowptr, p.esrc, p.inv_sqrt, p.h2, p.b2, p.agg2);
    grid.sync();

    // -- phase 9: stats over agg2
    for (int w = bid; w < STATS_NB; w += nb)
        stats_item(w, t, p.agg2, p.stats2, red);
    grid.sync();

    // -- phase 10: layer-3 GEMM (BN(g2,bt2)+ReLU fused, NCOL=64)
    for (int w = bid; w < GEMM_NB; w += nb)
        gemm_body<64, true, true>(w * 64, t, p.agg2, p.Wf3, p.stats2,
                                  p.g2, p.bt2, p.h3, As, sc_s, sh_s);
    grid.sync();

    // -- phase 11: layer-3 aggregate straight into d_out (fp32)
    for (int w = bid; w < AGG64_NB; w += nb)
        agg_item<64, false>(w, t, p.rowptr, p.esrc, p.inv_sqrt, p.h3, p.b3, p.out);
}

// ---------------------------------------------------------------------------
extern "C" void kernel_launch(void* const* d_in, const int* in_sizes, int n_in,
                              void* d_out, int out_size, void* d_ws, size_t ws_size,
                              hipStream_t stream) {
    MegaParams p;
    p.ei  = (const int*)d_in[1];
    p.x   = (const float*)d_in[0];
    p.W1  = (const float*)d_in[2];
    p.b1  = (const float*)d_in[3];
    p.g1  = (const float*)d_in[4];
    p.bt1 = (const float*)d_in[5];
    p.W2  = (const float*)d_in[6];
    p.b2  = (const float*)d_in[7];
    p.g2  = (const float*)d_in[8];
    p.bt2 = (const float*)d_in[9];
    p.W3  = (const float*)d_in[10];
    p.b3  = (const float*)d_in[11];
    p.out = (float*)d_out;

    char* ws = (char*)d_ws;
    size_t off = 0;
    auto alloc = [&](size_t bytes) { char* q = ws + off; off += (bytes + 255) & ~(size_t)255; return q; };
    // contiguous zero-init region: deg | stats1 | stats2 (zeroed in phase 0)
    p.deg     = (int*)  alloc((size_t)N_NODES * 4);
    p.stats1  = (float*)alloc(256 * 4);
    p.stats2  = (float*)alloc(256 * 4);
    const size_t zbytes = (size_t)((char*)(p.stats2 + 256) - (char*)p.deg);
    p.zero16  = (int)(zbytes / 16);
    p.inv_sqrt = (float*)alloc((size_t)N_NODES * 4);
    p.excl     = (int*)  alloc((size_t)N_NODES * 4);
    p.partials = (int*)  alloc(256 * 4);
    p.rowptr   = (int*)  alloc((size_t)(N_NODES + 1) * 4);
    p.rank     = (int*)  alloc((size_t)N_EDGES * 4);
    p.esrc     = (int*)  alloc((size_t)N_EDGES * 4);
    p.Wf1 = (unsigned short*)alloc((size_t)128 * 128 * 2);
    p.Wf2 = (unsigned short*)alloc((size_t)128 * 128 * 2);
    p.Wf3 = (unsigned short*)alloc((size_t)64 * 128 * 2);
    p.h1  = (unsigned short*)alloc((size_t)N_NODES * 128 * 2);
    p.h2  = (unsigned short*)alloc((size_t)N_NODES * 128 * 2);
    p.h3  = (unsigned short*)alloc((size_t)N_NODES * 64 * 2);
    p.agg1 = (unsigned short*)alloc((size_t)N_NODES * 128 * 2);
    p.agg2 = (unsigned short*)alloc((size_t)N_NODES * 128 * 2);

    // grid = max co-resident blocks (grid-stride phases work at any size)
    int maxB = 0;
    hipOccupancyMaxActiveBlocksPerMultiprocessor(&maxB, k_mega, 256, 0);
    if (maxB < 1) maxB = 1;
    int grid = maxB * 256;            // 256 CUs on MI355X
    if (grid > 2048) grid = 2048;

    void* args[] = { &p };
    hipLaunchCooperativeKernel((void*)k_mega, dim3(grid), dim3(256), args, 0, stream);
}

// Round 11
// 321.142 us; speedup vs baseline: 2.9474x; 2.9474x over previous
//
#include <hip/hip_runtime.h>

#define N_NODES 50000
#define N_EDGES 800000
static constexpr float EPS = 1e-5f;
static constexpr int SCAN_NB = (N_NODES + 255) / 256;   // 196
static constexpr int GEMM_NB = (N_NODES + 63) / 64;     // 782
static constexpr int FILL_NB = (N_EDGES + 1023) / 1024; // 782 (4 edges/thread)

using bf16x8 = __attribute__((ext_vector_type(8))) short;  // 8 bf16 (4 VGPRs)
using f32x4  = __attribute__((ext_vector_type(4))) float;

// ---- bf16 helpers (raw-bit, RNE) ----
static __device__ __forceinline__ unsigned short f2bf(float f) {
    unsigned int u = __float_as_uint(f);
    return (unsigned short)((u + 0x7FFFu + ((u >> 16) & 1u)) >> 16);
}
static __device__ __forceinline__ float blo(unsigned int w) { return __uint_as_float(w << 16); }
static __device__ __forceinline__ float bhi(unsigned int w) { return __uint_as_float(w & 0xffff0000u); }

// ---------------------------------------------------------------------------
// W -> bf16 fragment packing + zero-init of deg|stats1|stats2 (one launch)
// 160 blocks: wconv items 40960; zeroing grid-strided over the same threads.
// ---------------------------------------------------------------------------
__global__ __launch_bounds__(256) void k_wconv_zero(
    const float* __restrict__ W1, const float* __restrict__ W2,
    const float* __restrict__ W3,
    unsigned short* __restrict__ Wf1, unsigned short* __restrict__ Wf2,
    unsigned short* __restrict__ Wf3,
    int4* __restrict__ zbase, int zero16) {
    int gid = blockIdx.x * 256 + threadIdx.x;   // < 40960
    for (int i = gid; i < zero16; i += 160 * 256)
        zbase[i] = make_int4(0, 0, 0, 0);
    const float* W; unsigned short* Wf; int NCOL, idx;
    if (gid < 16384)      { W = W1; Wf = Wf1; NCOL = 128; idx = gid; }
    else if (gid < 32768) { W = W2; Wf = Wf2; NCOL = 128; idx = gid - 16384; }
    else                  { W = W3; Wf = Wf3; NCOL = 64;  idx = gid - 32768; }
    int j  = idx & 7;
    int l  = (idx >> 3) & 63;
    int s  = (idx >> 9) & 3;
    int tn = idx >> 11;
    int n = tn * 16 + (l & 15);
    int k = s * 32 + (l >> 4) * 8 + j;
    Wf[idx] = f2bf(W[k * NCOL + n]);
}

// ---------------------------------------------------------------------------
// MFMA GEMM body: H(bf16) = act(A) @ W, act = BN+ReLU if BN.
// ---------------------------------------------------------------------------
template <int NCOL, bool BN, bool ABF16>
static __device__ __forceinline__ void gemm_body(
    int row0, int t,
    const void* __restrict__ Ap, const unsigned short* __restrict__ Wf,
    const float* __restrict__ stats,
    const float* __restrict__ gamma, const float* __restrict__ beta,
    unsigned short* __restrict__ H,
    unsigned short* As, float* sc_s, float* sh_s) {
    if (BN) {
        if (t < 128) {
            float s  = stats[t];
            float sq = stats[128 + t];
            float mean = s * (1.0f / N_NODES);
            float var  = sq * (1.0f / N_NODES) - mean * mean;
            float sc = gamma[t] * rsqrtf(var + EPS);
            sc_s[t] = sc;
            sh_s[t] = beta[t] - mean * sc;
        }
        __syncthreads();
    }

#pragma unroll
    for (int i = 0; i < 4; i++) {
        int q = i * 256 + t;
        int row = q >> 4;
        int c8  = (q & 15) * 8;
        int grow = row0 + row;
        float v[8];
        if (grow < N_NODES) {
            if (ABF16) {
                uint4 p = *(const uint4*)((const unsigned short*)Ap + (size_t)grow * 128 + c8);
                v[0] = blo(p.x); v[1] = bhi(p.x); v[2] = blo(p.y); v[3] = bhi(p.y);
                v[4] = blo(p.z); v[5] = bhi(p.z); v[6] = blo(p.w); v[7] = bhi(p.w);
            } else {
                const float* Af = (const float*)Ap + (size_t)grow * 128 + c8;
                float4 f0 = *(const float4*)Af;
                float4 f1 = *(const float4*)(Af + 4);
                v[0] = f0.x; v[1] = f0.y; v[2] = f0.z; v[3] = f0.w;
                v[4] = f1.x; v[5] = f1.y; v[6] = f1.z; v[7] = f1.w;
            }
        } else {
#pragma unroll
            for (int j = 0; j < 8; j++) v[j] = 0.f;
        }
        if (BN) {
#pragma unroll
            for (int j = 0; j < 8; j++)
                v[j] = fmaxf(fmaf(v[j], sc_s[c8 + j], sh_s[c8 + j]), 0.f);
        }
        uint4 pk;
        pk.x = (unsigned)f2bf(v[0]) | ((unsigned)f2bf(v[1]) << 16);
        pk.y = (unsigned)f2bf(v[2]) | ((unsigned)f2bf(v[3]) << 16);
        pk.z = (unsigned)f2bf(v[4]) | ((unsigned)f2bf(v[5]) << 16);
        pk.w = (unsigned)f2bf(v[6]) | ((unsigned)f2bf(v[7]) << 16);
        *(uint4*)&As[row * 136 + c8] = pk;
    }
    __syncthreads();

    const int wv = t >> 6;
    const int l  = t & 63;
    const int m  = l & 15;
    const int kq = l >> 4;

    bf16x8 afrag[4];
    const unsigned short* arow = &As[(wv * 16 + m) * 136 + kq * 8];
#pragma unroll
    for (int s = 0; s < 4; s++)
        afrag[s] = *(const bf16x8*)(arow + s * 32);

    constexpr int NT = NCOL / 16;
#pragma unroll
    for (int tn = 0; tn < NT; tn++) {
        f32x4 acc = {0.f, 0.f, 0.f, 0.f};
#pragma unroll
        for (int s = 0; s < 4; s++) {
            bf16x8 b = *(const bf16x8*)&Wf[(size_t)((tn * 4 + s) * 64 + l) * 8];
            acc = __builtin_amdgcn_mfma_f32_16x16x32_bf16(afrag[s], b, acc, 0, 0, 0);
        }
        int col = tn * 16 + m;
#pragma unroll
        for (int r = 0; r < 4; r++) {
            int row = row0 + wv * 16 + kq * 4 + r;
            if (row < N_NODES) H[(size_t)row * NCOL + col] = f2bf(acc[r]);
        }
    }
}

// standalone GEMM kernels for layers 2/3
template <int NCOL>
__global__ __launch_bounds__(256) void k_gemm_bn(
    const unsigned short* __restrict__ A, const unsigned short* __restrict__ Wf,
    const float* __restrict__ stats,
    const float* __restrict__ gamma, const float* __restrict__ beta,
    unsigned short* __restrict__ H) {
    __shared__ unsigned short As[64 * 136];
    __shared__ float sc_s[128], sh_s[128];
    gemm_body<NCOL, true, true>(blockIdx.x * 64, threadIdx.x, A, Wf, stats,
                                gamma, beta, H, As, sc_s, sh_s);
}

// ---------------------------------------------------------------------------
// fused: blocks [0,FILL_NB) = histogram + per-edge rank (atomic pipe);
//        blocks [FILL_NB,...) = layer-1 GEMM (MFMA pipe).
// ---------------------------------------------------------------------------
__global__ __launch_bounds__(256) void k_prep_gemm1(
    const int* __restrict__ ei, int* __restrict__ deg, int* __restrict__ rank,
    const float* __restrict__ x, const unsigned short* __restrict__ Wf1,
    unsigned short* __restrict__ h1) {
    __shared__ unsigned short As[64 * 136];
    __shared__ float sc_s[128], sh_s[128];
    if (blockIdx.x < FILL_NB) {
        int e0 = (blockIdx.x * 256 + threadIdx.x) * 4;
        if (e0 >= N_EDGES) return;          // N_EDGES % 4 == 0
        int4 d4 = *(const int4*)&ei[N_EDGES + e0];
        int4 r;
        r.x = atomicAdd(&deg[d4.x], 1);
        r.y = atomicAdd(&deg[d4.y], 1);
        r.z = atomicAdd(&deg[d4.z], 1);
        r.w = atomicAdd(&deg[d4.w], 1);
        *(int4*)&rank[e0] = r;
    } else {
        gemm_body<128, false, false>((blockIdx.x - FILL_NB) * 64, threadIdx.x,
                                     x, Wf1, nullptr, nullptr, nullptr, h1,
                                     As, sc_s, sh_s);
    }
}

// ---------------------------------------------------------------------------
// scan stage 1: block-local exclusive scan of deg + block totals + inv_sqrt
// ---------------------------------------------------------------------------
__global__ __launch_bounds__(256) void k_scan1(const int* __restrict__ deg,
                                               float* __restrict__ inv_sqrt,
                                               int* __restrict__ excl,
                                               int* __restrict__ partials) {
    const int t = threadIdx.x;
    const int i = blockIdx.x * 256 + t;
    int v = (i < N_NODES) ? deg[i] : 0;
    if (i < N_NODES) inv_sqrt[i] = rsqrtf((float)v + 1.0f);
    __shared__ int sh[256];
    sh[t] = v;
    __syncthreads();
    for (int off = 1; off < 256; off <<= 1) {
        int u = (t >= off) ? sh[t - off] : 0;
        __syncthreads();
        sh[t] += u;
        __syncthreads();
    }
    if (i < N_NODES) excl[i] = sh[t] - v;
    if (t == 255) partials[blockIdx.x] = sh[t];
}

// ---------------------------------------------------------------------------
// fused scan23 + fill (both depend only on scan1 outputs):
// every block scans the 196 partials in LDS (784 B);
// blocks [0,SCAN_NB): rowptr[i] = excl[i] + ps[block]
// blocks [SCAN_NB,+FILL_NB): esrc[excl[d] + ps[d>>8] + rank] = src (atomic-free)
// ---------------------------------------------------------------------------
__global__ __launch_bounds__(256) void k_scan23_fill(
    const int* __restrict__ excl, const int* __restrict__ partials,
    int* __restrict__ rowptr,
    const int* __restrict__ ei, const int* __restrict__ rank,
    int* __restrict__ esrc) {
    const int t = threadIdx.x;
    __shared__ int sh[256];
    __shared__ int ps[256];
    int v = (t < SCAN_NB) ? partials[t] : 0;
    sh[t] = v;
    __syncthreads();
    for (int off = 1; off < 256; off <<= 1) {
        int u = (t >= off) ? sh[t - off] : 0;
        __syncthreads();
        sh[t] += u;
        __syncthreads();
    }
    ps[t] = sh[t] - v;          // exclusive prefix of scan-block t
    __syncthreads();

    if (blockIdx.x < SCAN_NB) {
        const int i = blockIdx.x * 256 + t;
        if (i < N_NODES) rowptr[i] = excl[i] + ps[blockIdx.x];
        if (i == 0) rowptr[N_NODES] = N_EDGES;
    } else {
        int e0 = ((blockIdx.x - SCAN_NB) * 256 + t) * 4;
        if (e0 < N_EDGES) {
            int4 s4 = *(const int4*)&ei[e0];
            int4 d4 = *(const int4*)&ei[N_EDGES + e0];
            int4 r4 = *(const int4*)&rank[e0];
            int p0 = excl[d4.x] + ps[d4.x >> 8] + r4.x;
            int p1 = excl[d4.y] + ps[d4.y >> 8] + r4.y;
            int p2 = excl[d4.z] + ps[d4.z >> 8] + r4.z;
            int p3 = excl[d4.w] + ps[d4.w >> 8] + r4.w;
            esrc[p0] = s4.x;
            esrc[p1] = s4.y;
            esrc[p2] = s4.z;
            esrc[p3] = s4.w;
        }
    }
}

// ---------------------------------------------------------------------------
// CSR gather-aggregate from bf16 H, fp32 accumulate, 8-wide edge unroll,
// 16 B/lane (uint4 = 8 bf16). coef = inv_sqrt[s] * inv_sqrt[node] on the fly.
// ---------------------------------------------------------------------------
template <int F, bool OUTBF>
__global__ __launch_bounds__(256) void k_agg(const int* __restrict__ rowptr,
                                             const int* __restrict__ esrc,
                                             const float* __restrict__ inv_sqrt,
                                             const unsigned short* __restrict__ H,
                                             const float* __restrict__ bias,
                                             void* __restrict__ OUT) {
    constexpr int LPN = F / 8;              // lanes per node (16 or 8), uint4 each
    constexpr int NPB = 256 / LPN;          // nodes per block (16 or 32)
    const int t = threadIdx.x;
    const int node = blockIdx.x * NPB + t / LPN;
    const int lane = t % LPN;
    if (node >= N_NODES) return;

    const uint4* __restrict__ Hv = (const uint4*)H;   // 8 bf16 per uint4
    const int beg = rowptr[node];
    const int end = rowptr[node + 1];
    const float rsn = inv_sqrt[node];

    float acc[8];
#pragma unroll
    for (int i = 0; i < 8; i++) acc[i] = 0.f;

#define ACC8(P, C)                                                     \
    acc[0] = fmaf(blo((P).x), (C), acc[0]);                            \
    acc[1] = fmaf(bhi((P).x), (C), acc[1]);                            \
    acc[2] = fmaf(blo((P).y), (C), acc[2]);                            \
    acc[3] = fmaf(bhi((P).y), (C), acc[3]);                            \
    acc[4] = fmaf(blo((P).z), (C), acc[4]);                            \
    acc[5] = fmaf(bhi((P).z), (C), acc[5]);                            \
    acc[6] = fmaf(blo((P).w), (C), acc[6]);                            \
    acc[7] = fmaf(bhi((P).w), (C), acc[7]);

    int j = beg;
    // 8-wide: 8 independent H-row gathers in flight per lane
    for (; j + 7 < end; j += 8) {
        int4 sa = *(const int4*)&esrc[j];
        int4 sb = *(const int4*)&esrc[j + 4];
        uint4 p0 = Hv[(size_t)sa.x * LPN + lane];
        uint4 p1 = Hv[(size_t)sa.y * LPN + lane];
        uint4 p2 = Hv[(size_t)sa.z * LPN + lane];
        uint4 p3 = Hv[(size_t)sa.w * LPN + lane];
        uint4 p4 = Hv[(size_t)sb.x * LPN + lane];
        uint4 p5 = Hv[(size_t)sb.y * LPN + lane];
        uint4 p6 = Hv[(size_t)sb.z * LPN + lane];
        uint4 p7 = Hv[(size_t)sb.w * LPN + lane];
        float c0 = inv_sqrt[sa.x] * rsn, c1 = inv_sqrt[sa.y] * rsn;
        float c2 = inv_sqrt[sa.z] * rsn, c3 = inv_sqrt[sa.w] * rsn;
        float c4 = inv_sqrt[sb.x] * rsn, c5 = inv_sqrt[sb.y] * rsn;
        float c6 = inv_sqrt[sb.z] * rsn, c7 = inv_sqrt[sb.w] * rsn;
        ACC8(p0, c0) ACC8(p1, c1) ACC8(p2, c2) ACC8(p3, c3)
        ACC8(p4, c4) ACC8(p5, c5) ACC8(p6, c6) ACC8(p7, c7)
    }
    if (j + 3 < end) {
        int4 sa = *(const int4*)&esrc[j];
        uint4 p0 = Hv[(size_t)sa.x * LPN + lane];
        uint4 p1 = Hv[(size_t)sa.y * LPN + lane];
        uint4 p2 = Hv[(size_t)sa.z * LPN + lane];
        uint4 p3 = Hv[(size_t)sa.w * LPN + lane];
        float c0 = inv_sqrt[sa.x] * rsn, c1 = inv_sqrt[sa.y] * rsn;
        float c2 = inv_sqrt[sa.z] * rsn, c3 = inv_sqrt[sa.w] * rsn;
        ACC8(p0, c0) ACC8(p1, c1) ACC8(p2, c2) ACC8(p3, c3)
        j += 4;
    }
    for (; j < end; j++) {
        int s0 = esrc[j];
        float c0 = inv_sqrt[s0] * rsn;
        uint4 p0 = Hv[(size_t)s0 * LPN + lane];
        ACC8(p0, c0)
    }
#undef ACC8

    // self-loop + bias (self coef = rsn^2)
    uint4 ps = Hv[(size_t)node * LPN + lane];
    float idv = rsn * rsn;
    float4 b0 = ((const float4*)bias)[lane * 2];
    float4 b1 = ((const float4*)bias)[lane * 2 + 1];
    acc[0] = fmaf(blo(ps.x), idv, acc[0]) + b0.x;
    acc[1] = fmaf(bhi(ps.x), idv, acc[1]) + b0.y;
    acc[2] = fmaf(blo(ps.y), idv, acc[2]) + b0.z;
    acc[3] = fmaf(bhi(ps.y), idv, acc[3]) + b0.w;
    acc[4] = fmaf(blo(ps.z), idv, acc[4]) + b1.x;
    acc[5] = fmaf(bhi(ps.z), idv, acc[5]) + b1.y;
    acc[6] = fmaf(blo(ps.w), idv, acc[6]) + b1.z;
    acc[7] = fmaf(bhi(ps.w), idv, acc[7]) + b1.w;

    if (OUTBF) {
        uint4 pk;
        pk.x = (unsigned)f2bf(acc[0]) | ((unsigned)f2bf(acc[1]) << 16);
        pk.y = (unsigned)f2bf(acc[2]) | ((unsigned)f2bf(acc[3]) << 16);
        pk.z = (unsigned)f2bf(acc[4]) | ((unsigned)f2bf(acc[5]) << 16);
        pk.w = (unsigned)f2bf(acc[6]) | ((unsigned)f2bf(acc[7]) << 16);
        ((uint4*)OUT)[(size_t)node * LPN + lane] = pk;
    } else {
        float4* o = (float4*)OUT + ((size_t)node * LPN + lane) * 2;
        o[0] = make_float4(acc[0], acc[1], acc[2], acc[3]);
        o[1] = make_float4(acc[4], acc[5], acc[6], acc[7]);
    }
}

// ---------------------------------------------------------------------------
// column stats over bf16 A[N,128]
// ---------------------------------------------------------------------------
__global__ __launch_bounds__(256) void k_stats(const unsigned short* __restrict__ A,
                                               float* __restrict__ stats) {
    const int t  = threadIdx.x;
    const int c4 = t & 31;
    const int rr = t >> 5;
    float4 sum = make_float4(0.f, 0.f, 0.f, 0.f);
    float4 sq  = make_float4(0.f, 0.f, 0.f, 0.f);
    for (int row = blockIdx.x * 8 + rr; row < N_NODES; row += gridDim.x * 8) {
        uint2 p = *(const uint2*)&A[(size_t)row * 128 + c4 * 4];
        float vx = blo(p.x), vy = bhi(p.x), vz = blo(p.y), vw = bhi(p.y);
        sum.x += vx; sum.y += vy; sum.z += vz; sum.w += vw;
        sq.x += vx * vx; sq.y += vy * vy; sq.z += vz * vz; sq.w += vw * vw;
    }
    __shared__ float4 red[2][8][32];
    red[0][rr][c4] = sum;
    red[1][rr][c4] = sq;
    __syncthreads();
    if (t < 32) {
        float4 s = make_float4(0.f, 0.f, 0.f, 0.f);
        float4 q = make_float4(0.f, 0.f, 0.f, 0.f);
#pragma unroll
        for (int i = 0; i < 8; i++) {
            float4 a = red[0][i][t];
            float4 b = red[1][i][t];
            s.x += a.x; s.y += a.y; s.z += a.z; s.w += a.w;
            q.x += b.x; q.y += b.y; q.z += b.z; q.w += b.w;
        }
        int c = t * 4;
        atomicAdd(&stats[c + 0], s.x); atomicAdd(&stats[c + 1], s.y);
        atomicAdd(&stats[c + 2], s.z); atomicAdd(&stats[c + 3], s.w);
        atomicAdd(&stats[128 + c + 0], q.x); atomicAdd(&stats[128 + c + 1], q.y);
        atomicAdd(&stats[128 + c + 2], q.z); atomicAdd(&stats[128 + c + 3], q.w);
    }
}

// ---------------------------------------------------------------------------
extern "C" void kernel_launch(void* const* d_in, const int* in_sizes, int n_in,
                              void* d_out, int out_size, void* d_ws, size_t ws_size,
                              hipStream_t stream) {
    const float* x   = (const float*)d_in[0];
    const int*   ei  = (const int*)d_in[1];
    const float* W1  = (const float*)d_in[2];
    const float* b1  = (const float*)d_in[3];
    const float* g1  = (const float*)d_in[4];
    const float* bt1 = (const float*)d_in[5];
    const float* W2  = (const float*)d_in[6];
    const float* b2  = (const float*)d_in[7];
    const float* g2  = (const float*)d_in[8];
    const float* bt2 = (const float*)d_in[9];
    const float* W3  = (const float*)d_in[10];
    const float* b3  = (const float*)d_in[11];
    float* out = (float*)d_out;                 // [N, 64] fp32

    char* ws = (char*)d_ws;
    size_t off = 0;
    auto alloc = [&](size_t bytes) { char* p = ws + off; off += (bytes + 255) & ~(size_t)255; return p; };
    // contiguous zero-init region: deg | stats1 | stats2 (zeroed in k_wconv_zero)
    int*   deg      = (int*)  alloc((size_t)N_NODES * 4);
    float* stats1   = (float*)alloc(256 * 4);
    float* stats2   = (float*)alloc(256 * 4);
    const size_t zbytes = (size_t)((char*)(stats2 + 256) - (char*)deg);
    const int zero16 = (int)(zbytes / 16);
    float* inv_sqrt = (float*)alloc((size_t)N_NODES * 4);
    int*   excl     = (int*)  alloc((size_t)N_NODES * 4);
    int*   partials = (int*)  alloc(256 * 4);
    int*   rowptr   = (int*)  alloc((size_t)(N_NODES + 1) * 4);
    int*   rank     = (int*)  alloc((size_t)N_EDGES * 4);
    int*   esrc     = (int*)  alloc((size_t)N_EDGES * 4);
    unsigned short* Wf1 = (unsigned short*)alloc((size_t)128 * 128 * 2);
    unsigned short* Wf2 = (unsigned short*)alloc((size_t)128 * 128 * 2);
    unsigned short* Wf3 = (unsigned short*)alloc((size_t)64 * 128 * 2);
    unsigned short* h1  = (unsigned short*)alloc((size_t)N_NODES * 128 * 2);
    unsigned short* h2  = (unsigned short*)alloc((size_t)N_NODES * 128 * 2);
    unsigned short* h3  = (unsigned short*)alloc((size_t)N_NODES * 64 * 2);
    unsigned short* agg1 = (unsigned short*)alloc((size_t)N_NODES * 128 * 2);
    unsigned short* agg2 = (unsigned short*)alloc((size_t)N_NODES * 128 * 2);

    // 1: pack weights + zero deg/stats
    k_wconv_zero<<<160, 256, 0, stream>>>(W1, W2, W3, Wf1, Wf2, Wf3,
                                          (int4*)deg, zero16);
    // 2: histogram+rank (atomic pipe) || layer-1 GEMM (MFMA pipe)
    k_prep_gemm1<<<FILL_NB + GEMM_NB, 256, 0, stream>>>(ei, deg, rank, x, Wf1, h1);
    // 3: scan stage 1
    k_scan1<<<SCAN_NB, 256, 0, stream>>>(deg, inv_sqrt, excl, partials);
    // 4: scan stages 2+3 || CSR fill (both depend only on scan1)
    k_scan23_fill<<<SCAN_NB + FILL_NB, 256, 0, stream>>>(excl, partials, rowptr,
                                                         ei, rank, esrc);
    // 5-6: layer 1 aggregate + stats
    k_agg<128, true><<<N_NODES / 16, 256, 0, stream>>>(rowptr, esrc, inv_sqrt, h1, b1, agg1);
    k_stats<<<256, 256, 0, stream>>>(agg1, stats1);
    // 7-9: layer 2
    k_gemm_bn<128><<<GEMM_NB, 256, 0, stream>>>(agg1, Wf2, stats1, g1, bt1, h2);
    k_agg<128, true><<<N_NODES / 16, 256, 0, stream>>>(rowptr, esrc, inv_sqrt, h2, b2, agg2);
    k_stats<<<256, 256, 0, stream>>>(agg2, stats2);
    // 10-11: layer 3 (aggregate straight into d_out, fp32)
    k_gemm_bn<64><<<GEMM_NB, 256, 0, stream>>>(agg2, Wf3, stats2, g2, bt2, h3);
    k_agg<64, false><<<(N_NODES + 31) / 32, 256, 0, stream>>>(rowptr, esrc, inv_sqrt, h3, b3, out);
}

// Round 12
// 306.460 us; speedup vs baseline: 3.0886x; 1.0479x over previous
//
#include <hip/hip_runtime.h>

#define N_NODES 50000
#define N_EDGES 800000
static constexpr float EPS = 1e-5f;
static constexpr int NCH   = 16;                 // histogram chunks
static constexpr int EPC   = N_EDGES / NCH;      // 50000 edges per chunk
static constexpr int NW    = (N_NODES + 3) / 4;  // 12500 byte-packed words
static constexpr int SCAN_NB = (N_NODES + 1023) / 1024;   // 49 (4 nodes/thread)
static constexpr int GEMM_NB = (N_NODES + 63) / 64;       // 782
static constexpr int FILL_NB = (N_EDGES + 1023) / 1024;   // 782 (4 edges/thread)
static constexpr int WCONV_NB = 160;

using bf16x8 = __attribute__((ext_vector_type(8))) short;  // 8 bf16 (4 VGPRs)
using f32x4  = __attribute__((ext_vector_type(4))) float;

// ---- bf16 helpers (raw-bit, RNE) ----
static __device__ __forceinline__ unsigned short f2bf(float f) {
    unsigned int u = __float_as_uint(f);
    return (unsigned short)((u + 0x7FFFu + ((u >> 16) & 1u)) >> 16);
}
static __device__ __forceinline__ float blo(unsigned int w) { return __uint_as_float(w << 16); }
static __device__ __forceinline__ float bhi(unsigned int w) { return __uint_as_float(w & 0xffff0000u); }

// ---------------------------------------------------------------------------
// fused: blocks [0,NCH) = per-chunk LDS byte-packed histogram + local rank
//        blocks [NCH,..) = W->bf16 fragment packing + stats zeroing
// LDS histogram: 50000 byte counters packed 4/word (50 KB). LDS atomic return
// gives the edge's rank within (chunk,dst). Global atomics: ZERO.
// ---------------------------------------------------------------------------
__global__ __launch_bounds__(256) void k_hist_wconv(
    const int* __restrict__ ei, unsigned char* __restrict__ rank8,
    unsigned int* __restrict__ basesU,
    const float* __restrict__ W1, const float* __restrict__ W2,
    const float* __restrict__ W3,
    unsigned short* __restrict__ Wf1, unsigned short* __restrict__ Wf2,
    unsigned short* __restrict__ Wf3, int4* __restrict__ statz) {
    __shared__ unsigned int h[NW];   // 50 KB
    const int t = threadIdx.x;
    if (blockIdx.x < NCH) {
        for (int i = t; i < NW; i += 256) h[i] = 0;
        __syncthreads();
        const int cbeg = blockIdx.x * EPC;
        for (int e0 = cbeg + t * 4; e0 < cbeg + EPC; e0 += 1024) {
            int4 d4 = *(const int4*)&ei[N_EDGES + e0];
            int sh0 = (d4.x & 3) * 8, sh1 = (d4.y & 3) * 8;
            int sh2 = (d4.z & 3) * 8, sh3 = (d4.w & 3) * 8;
            unsigned int o0 = atomicAdd(&h[d4.x >> 2], 1u << sh0);
            unsigned int o1 = atomicAdd(&h[d4.y >> 2], 1u << sh1);
            unsigned int o2 = atomicAdd(&h[d4.z >> 2], 1u << sh2);
            unsigned int o3 = atomicAdd(&h[d4.w >> 2], 1u << sh3);
            unsigned int pk = ((o0 >> sh0) & 0xffu) | (((o1 >> sh1) & 0xffu) << 8)
                            | (((o2 >> sh2) & 0xffu) << 16) | (((o3 >> sh3) & 0xffu) << 24);
            *(unsigned int*)&rank8[e0] = pk;
        }
        __syncthreads();
        for (int i = t; i < NW; i += 256)
            basesU[blockIdx.x * NW + i] = h[i];
    } else {
        int gid = (blockIdx.x - NCH) * 256 + t;   // < 40960
        if (gid < 128) statz[gid] = make_int4(0, 0, 0, 0);   // 2 KB stats region
        const float* W; unsigned short* Wf; int NCOL, idx;
        if (gid < 16384)      { W = W1; Wf = Wf1; NCOL = 128; idx = gid; }
        else if (gid < 32768) { W = W2; Wf = Wf2; NCOL = 128; idx = gid - 16384; }
        else                  { W = W3; Wf = Wf3; NCOL = 64;  idx = gid - 32768; }
        int j  = idx & 7;
        int l  = (idx >> 3) & 63;
        int s  = (idx >> 9) & 3;
        int tn = idx >> 11;
        int n = tn * 16 + (l & 15);
        int k = s * 32 + (l >> 4) * 8 + j;
        Wf[idx] = f2bf(W[k * NCOL + n]);
    }
}

// ---------------------------------------------------------------------------
// MFMA GEMM body: H(bf16) = act(A) @ W, act = BN+ReLU if BN.
// ---------------------------------------------------------------------------
template <int NCOL, bool BN, bool ABF16>
static __device__ __forceinline__ void gemm_body(
    int row0, int t,
    const void* __restrict__ Ap, const unsigned short* __restrict__ Wf,
    const float* __restrict__ stats,
    const float* __restrict__ gamma, const float* __restrict__ beta,
    unsigned short* __restrict__ H,
    unsigned short* As, float* sc_s, float* sh_s) {
    if (BN) {
        if (t < 128) {
            float s  = stats[t];
            float sq = stats[128 + t];
            float mean = s * (1.0f / N_NODES);
            float var  = sq * (1.0f / N_NODES) - mean * mean;
            float sc = gamma[t] * rsqrtf(var + EPS);
            sc_s[t] = sc;
            sh_s[t] = beta[t] - mean * sc;
        }
        __syncthreads();
    }

#pragma unroll
    for (int i = 0; i < 4; i++) {
        int q = i * 256 + t;
        int row = q >> 4;
        int c8  = (q & 15) * 8;
        int grow = row0 + row;
        float v[8];
        if (grow < N_NODES) {
            if (ABF16) {
                uint4 p = *(const uint4*)((const unsigned short*)Ap + (size_t)grow * 128 + c8);
                v[0] = blo(p.x); v[1] = bhi(p.x); v[2] = blo(p.y); v[3] = bhi(p.y);
                v[4] = blo(p.z); v[5] = bhi(p.z); v[6] = blo(p.w); v[7] = bhi(p.w);
            } else {
                const float* Af = (const float*)Ap + (size_t)grow * 128 + c8;
                float4 f0 = *(const float4*)Af;
                float4 f1 = *(const float4*)(Af + 4);
                v[0] = f0.x; v[1] = f0.y; v[2] = f0.z; v[3] = f0.w;
                v[4] = f1.x; v[5] = f1.y; v[6] = f1.z; v[7] = f1.w;
            }
        } else {
#pragma unroll
            for (int j = 0; j < 8; j++) v[j] = 0.f;
        }
        if (BN) {
#pragma unroll
            for (int j = 0; j < 8; j++)
                v[j] = fmaxf(fmaf(v[j], sc_s[c8 + j], sh_s[c8 + j]), 0.f);
        }
        uint4 pk;
        pk.x = (unsigned)f2bf(v[0]) | ((unsigned)f2bf(v[1]) << 16);
        pk.y = (unsigned)f2bf(v[2]) | ((unsigned)f2bf(v[3]) << 16);
        pk.z = (unsigned)f2bf(v[4]) | ((unsigned)f2bf(v[5]) << 16);
        pk.w = (unsigned)f2bf(v[6]) | ((unsigned)f2bf(v[7]) << 16);
        *(uint4*)&As[row * 136 + c8] = pk;
    }
    __syncthreads();

    const int wv = t >> 6;
    const int l  = t & 63;
    const int m  = l & 15;
    const int kq = l >> 4;

    bf16x8 afrag[4];
    const unsigned short* arow = &As[(wv * 16 + m) * 136 + kq * 8];
#pragma unroll
    for (int s = 0; s < 4; s++)
        afrag[s] = *(const bf16x8*)(arow + s * 32);

    constexpr int NT = NCOL / 16;
#pragma unroll
    for (int tn = 0; tn < NT; tn++) {
        f32x4 acc = {0.f, 0.f, 0.f, 0.f};
#pragma unroll
        for (int s = 0; s < 4; s++) {
            bf16x8 b = *(const bf16x8*)&Wf[(size_t)((tn * 4 + s) * 64 + l) * 8];
            acc = __builtin_amdgcn_mfma_f32_16x16x32_bf16(afrag[s], b, acc, 0, 0, 0);
        }
        int col = tn * 16 + m;
#pragma unroll
        for (int r = 0; r < 4; r++) {
            int row = row0 + wv * 16 + kq * 4 + r;
            if (row < N_NODES) H[(size_t)row * NCOL + col] = f2bf(acc[r]);
        }
    }
}

// standalone GEMM kernels for layers 2/3
template <int NCOL>
__global__ __launch_bounds__(256) void k_gemm_bn(
    const unsigned short* __restrict__ A, const unsigned short* __restrict__ Wf,
    const float* __restrict__ stats,
    const float* __restrict__ gamma, const float* __restrict__ beta,
    unsigned short* __restrict__ H) {
    __shared__ unsigned short As[64 * 136];
    __shared__ float sc_s[128], sh_s[128];
    gemm_body<NCOL, true, true>(blockIdx.x * 64, threadIdx.x, A, Wf, stats,
                                gamma, beta, H, As, sc_s, sh_s);
}

// ---------------------------------------------------------------------------
// fused: blocks [0,GEMM_NB) = layer-1 GEMM (MFMA pipe);
//        blocks [GEMM_NB,+SCAN_NB) = scan stage 1 over chunk bases:
//          per node: total deg over 16 chunks, in-place exclusive chunk bases
//          (byte-packed), inv_sqrt, block scan (4 nodes/thread) -> excl+partials
// ---------------------------------------------------------------------------
__global__ __launch_bounds__(256) void k_gemm1_scan1(
    const float* __restrict__ x, const unsigned short* __restrict__ Wf1,
    unsigned short* __restrict__ h1,
    unsigned int* __restrict__ basesU, float* __restrict__ inv_sqrt,
    int* __restrict__ excl, int* __restrict__ partials) {
    __shared__ unsigned short As[64 * 136];
    __shared__ float sc_s[128], sh_s[128];
    const int t = threadIdx.x;
    if (blockIdx.x < GEMM_NB) {
        gemm_body<128, false, false>(blockIdx.x * 64, t, x, Wf1,
                                     nullptr, nullptr, nullptr, h1, As, sc_s, sh_s);
    } else {
        int* shi = (int*)As;                      // reuse LDS
        const int g = (blockIdx.x - GEMM_NB) * 256 + t;   // node group (4 nodes)
        int r0 = 0, r1 = 0, r2 = 0, r3 = 0;
        if (g < NW) {
#pragma unroll
            for (int c = 0; c < NCH; c++) {
                unsigned int w = basesU[c * NW + g];
                unsigned int pb = (unsigned)r0 | ((unsigned)r1 << 8)
                                | ((unsigned)r2 << 16) | ((unsigned)r3 << 24);
                basesU[c * NW + g] = pb;          // in-place exclusive chunk base
                r0 += w & 0xff; r1 += (w >> 8) & 0xff;
                r2 += (w >> 16) & 0xff; r3 += (w >> 24) & 0xff;
            }
        }
        int S = r0 + r1 + r2 + r3;
        shi[t] = S;
        __syncthreads();
        for (int off = 1; off < 256; off <<= 1) {
            int u = (t >= off) ? shi[t - off] : 0;
            __syncthreads();
            shi[t] += u;
            __syncthreads();
        }
        int base = shi[t] - S;                    // exclusive prefix of this thread
        if (g < NW) {
            int i0 = g * 4;
            *(int4*)&excl[i0] = make_int4(base, base + r0, base + r0 + r1,
                                          base + r0 + r1 + r2);
            *(float4*)&inv_sqrt[i0] = make_float4(
                rsqrtf((float)r0 + 1.0f), rsqrtf((float)r1 + 1.0f),
                rsqrtf((float)r2 + 1.0f), rsqrtf((float)r3 + 1.0f));
        }
        if (t == 255) partials[blockIdx.x - GEMM_NB] = shi[t];
    }
}

// ---------------------------------------------------------------------------
// fused scan2 apply + CSR fill (both depend only on scan1 outputs):
// every block scans the 49 partials in LDS;
// blocks [0,SCAN_NB): rowptr[i] = excl[i] + ps[i>>10] (4 nodes/thread, int4)
// blocks [SCAN_NB,+FILL_NB): atomic-free fill:
//   pos = excl[d] + ps[d>>10] + cb8[chunk][d] + rank8[e]
// ---------------------------------------------------------------------------
__global__ __launch_bounds__(256) void k_scan2_fill(
    const int* __restrict__ excl, const int* __restrict__ partials,
    int* __restrict__ rowptr,
    const int* __restrict__ ei, const unsigned char* __restrict__ rank8,
    const unsigned char* __restrict__ cb8,
    int* __restrict__ esrc) {
    const int t = threadIdx.x;
    __shared__ int sh[256];
    __shared__ int ps[256];
    int v = (t < SCAN_NB) ? partials[t] : 0;
    sh[t] = v;
    __syncthreads();
    for (int off = 1; off < 256; off <<= 1) {
        int u = (t >= off) ? sh[t - off] : 0;
        __syncthreads();
        sh[t] += u;
        __syncthreads();
    }
    ps[t] = sh[t] - v;
    __syncthreads();

    if (blockIdx.x < SCAN_NB) {
        int i0 = (blockIdx.x * 256 + t) * 4;
        if (i0 < N_NODES) {
            int4 e4 = *(const int4*)&excl[i0];
            int b = ps[blockIdx.x];
            *(int4*)&rowptr[i0] = make_int4(e4.x + b, e4.y + b, e4.z + b, e4.w + b);
        }
        if (blockIdx.x == 0 && t == 0) rowptr[N_NODES] = N_EDGES;
    } else {
        int e0 = ((blockIdx.x - SCAN_NB) * 256 + t) * 4;
        if (e0 < N_EDGES) {
            const int c = e0 / EPC;               // group never straddles chunks
            const unsigned char* cb = cb8 + (size_t)c * N_NODES;
            int4 s4 = *(const int4*)&ei[e0];
            int4 d4 = *(const int4*)&ei[N_EDGES + e0];
            unsigned int r4 = *(const unsigned int*)&rank8[e0];
            int p0 = excl[d4.x] + ps[d4.x >> 10] + cb[d4.x] + (r4 & 0xff);
            int p1 = excl[d4.y] + ps[d4.y >> 10] + cb[d4.y] + ((r4 >> 8) & 0xff);
            int p2 = excl[d4.z] + ps[d4.z >> 10] + cb[d4.z] + ((r4 >> 16) & 0xff);
            int p3 = excl[d4.w] + ps[d4.w >> 10] + cb[d4.w] + ((r4 >> 24) & 0xff);
            esrc[p0] = s4.x;
            esrc[p1] = s4.y;
            esrc[p2] = s4.z;
            esrc[p3] = s4.w;
        }
    }
}

// ---------------------------------------------------------------------------
// CSR gather-aggregate from bf16 H, fp32 accumulate, 8-wide edge unroll,
// 16 B/lane (uint4 = 8 bf16). coef = inv_sqrt[s] * inv_sqrt[node] on the fly.
// ---------------------------------------------------------------------------
template <int F, bool OUTBF>
__global__ __launch_bounds__(256) void k_agg(const int* __restrict__ rowptr,
                                             const int* __restrict__ esrc,
                                             const float* __restrict__ inv_sqrt,
                                             const unsigned short* __restrict__ H,
                                             const float* __restrict__ bias,
                                             void* __restrict__ OUT) {
    constexpr int LPN = F / 8;              // lanes per node (16 or 8), uint4 each
    constexpr int NPB = 256 / LPN;          // nodes per block (16 or 32)
    const int t = threadIdx.x;
    const int node = blockIdx.x * NPB + t / LPN;
    const int lane = t % LPN;
    if (node >= N_NODES) return;

    const uint4* __restrict__ Hv = (const uint4*)H;   // 8 bf16 per uint4
    const int beg = rowptr[node];
    const int end = rowptr[node + 1];
    const float rsn = inv_sqrt[node];

    float acc[8];
#pragma unroll
    for (int i = 0; i < 8; i++) acc[i] = 0.f;

#define ACC8(P, C)                                                     \
    acc[0] = fmaf(blo((P).x), (C), acc[0]);                            \
    acc[1] = fmaf(bhi((P).x), (C), acc[1]);                            \
    acc[2] = fmaf(blo((P).y), (C), acc[2]);                            \
    acc[3] = fmaf(bhi((P).y), (C), acc[3]);                            \
    acc[4] = fmaf(blo((P).z), (C), acc[4]);                            \
    acc[5] = fmaf(bhi((P).z), (C), acc[5]);                            \
    acc[6] = fmaf(blo((P).w), (C), acc[6]);                            \
    acc[7] = fmaf(bhi((P).w), (C), acc[7]);

    int j = beg;
    for (; j + 7 < end; j += 8) {
        int4 sa = *(const int4*)&esrc[j];
        int4 sb = *(const int4*)&esrc[j + 4];
        uint4 p0 = Hv[(size_t)sa.x * LPN + lane];
        uint4 p1 = Hv[(size_t)sa.y * LPN + lane];
        uint4 p2 = Hv[(size_t)sa.z * LPN + lane];
        uint4 p3 = Hv[(size_t)sa.w * LPN + lane];
        uint4 p4 = Hv[(size_t)sb.x * LPN + lane];
        uint4 p5 = Hv[(size_t)sb.y * LPN + lane];
        uint4 p6 = Hv[(size_t)sb.z * LPN + lane];
        uint4 p7 = Hv[(size_t)sb.w * LPN + lane];
        float c0 = inv_sqrt[sa.x] * rsn, c1 = inv_sqrt[sa.y] * rsn;
        float c2 = inv_sqrt[sa.z] * rsn, c3 = inv_sqrt[sa.w] * rsn;
        float c4 = inv_sqrt[sb.x] * rsn, c5 = inv_sqrt[sb.y] * rsn;
        float c6 = inv_sqrt[sb.z] * rsn, c7 = inv_sqrt[sb.w] * rsn;
        ACC8(p0, c0) ACC8(p1, c1) ACC8(p2, c2) ACC8(p3, c3)
        ACC8(p4, c4) ACC8(p5, c5) ACC8(p6, c6) ACC8(p7, c7)
    }
    if (j + 3 < end) {
        int4 sa = *(const int4*)&esrc[j];
        uint4 p0 = Hv[(size_t)sa.x * LPN + lane];
        uint4 p1 = Hv[(size_t)sa.y * LPN + lane];
        uint4 p2 = Hv[(size_t)sa.z * LPN + lane];
        uint4 p3 = Hv[(size_t)sa.w * LPN + lane];
        float c0 = inv_sqrt[sa.x] * rsn, c1 = inv_sqrt[sa.y] * rsn;
        float c2 = inv_sqrt[sa.z] * rsn, c3 = inv_sqrt[sa.w] * rsn;
        ACC8(p0, c0) ACC8(p1, c1) ACC8(p2, c2) ACC8(p3, c3)
        j += 4;
    }
    for (; j < end; j++) {
        int s0 = esrc[j];
        float c0 = inv_sqrt[s0] * rsn;
        uint4 p0 = Hv[(size_t)s0 * LPN + lane];
        ACC8(p0, c0)
    }
#undef ACC8

    // self-loop + bias (self coef = rsn^2)
    uint4 ps = Hv[(size_t)node * LPN + lane];
    float idv = rsn * rsn;
    float4 b0 = ((const float4*)bias)[lane * 2];
    float4 b1 = ((const float4*)bias)[lane * 2 + 1];
    acc[0] = fmaf(blo(ps.x), idv, acc[0]) + b0.x;
    acc[1] = fmaf(bhi(ps.x), idv, acc[1]) + b0.y;
    acc[2] = fmaf(blo(ps.y), idv, acc[2]) + b0.z;
    acc[3] = fmaf(bhi(ps.y), idv, acc[3]) + b0.w;
    acc[4] = fmaf(blo(ps.z), idv, acc[4]) + b1.x;
    acc[5] = fmaf(bhi(ps.z), idv, acc[5]) + b1.y;
    acc[6] = fmaf(blo(ps.w), idv, acc[6]) + b1.z;
    acc[7] = fmaf(bhi(ps.w), idv, acc[7]) + b1.w;

    if (OUTBF) {
        uint4 pk;
        pk.x = (unsigned)f2bf(acc[0]) | ((unsigned)f2bf(acc[1]) << 16);
        pk.y = (unsigned)f2bf(acc[2]) | ((unsigned)f2bf(acc[3]) << 16);
        pk.z = (unsigned)f2bf(acc[4]) | ((unsigned)f2bf(acc[5]) << 16);
        pk.w = (unsigned)f2bf(acc[6]) | ((unsigned)f2bf(acc[7]) << 16);
        ((uint4*)OUT)[(size_t)node * LPN + lane] = pk;
    } else {
        float4* o = (float4*)OUT + ((size_t)node * LPN + lane) * 2;
        o[0] = make_float4(acc[0], acc[1], acc[2], acc[3]);
        o[1] = make_float4(acc[4], acc[5], acc[6], acc[7]);
    }
}

// ---------------------------------------------------------------------------
// column stats over bf16 A[N,128]
// ---------------------------------------------------------------------------
__global__ __launch_bounds__(256) void k_stats(const unsigned short* __restrict__ A,
                                               float* __restrict__ stats) {
    const int t  = threadIdx.x;
    const int c4 = t & 31;
    const int rr = t >> 5;
    float4 sum = make_float4(0.f, 0.f, 0.f, 0.f);
    float4 sq  = make_float4(0.f, 0.f, 0.f, 0.f);
    for (int row = blockIdx.x * 8 + rr; row < N_NODES; row += gridDim.x * 8) {
        uint2 p = *(const uint2*)&A[(size_t)row * 128 + c4 * 4];
        float vx = blo(p.x), vy = bhi(p.x), vz = blo(p.y), vw = bhi(p.y);
        sum.x += vx; sum.y += vy; sum.z += vz; sum.w += vw;
        sq.x += vx * vx; sq.y += vy * vy; sq.z += vz * vz; sq.w += vw * vw;
    }
    __shared__ float4 red[2][8][32];
    red[0][rr][c4] = sum;
    red[1][rr][c4] = sq;
    __syncthreads();
    if (t < 32) {
        float4 s = make_float4(0.f, 0.f, 0.f, 0.f);
        float4 q = make_float4(0.f, 0.f, 0.f, 0.f);
#pragma unroll
        for (int i = 0; i < 8; i++) {
            float4 a = red[0][i][t];
            float4 b = red[1][i][t];
            s.x += a.x; s.y += a.y; s.z += a.z; s.w += a.w;
            q.x += b.x; q.y += b.y; q.z += b.z; q.w += b.w;
        }
        int c = t * 4;
        atomicAdd(&stats[c + 0], s.x); atomicAdd(&stats[c + 1], s.y);
        atomicAdd(&stats[c + 2], s.z); atomicAdd(&stats[c + 3], s.w);
        atomicAdd(&stats[128 + c + 0], q.x); atomicAdd(&stats[128 + c + 1], q.y);
        atomicAdd(&stats[128 + c + 2], q.z); atomicAdd(&stats[128 + c + 3], q.w);
    }
}

// ---------------------------------------------------------------------------
extern "C" void kernel_launch(void* const* d_in, const int* in_sizes, int n_in,
                              void* d_out, int out_size, void* d_ws, size_t ws_size,
                              hipStream_t stream) {
    const float* x   = (const float*)d_in[0];
    const int*   ei  = (const int*)d_in[1];
    const float* W1  = (const float*)d_in[2];
    const float* b1  = (const float*)d_in[3];
    const float* g1  = (const float*)d_in[4];
    const float* bt1 = (const float*)d_in[5];
    const float* W2  = (const float*)d_in[6];
    const float* b2  = (const float*)d_in[7];
    const float* g2  = (const float*)d_in[8];
    const float* bt2 = (const float*)d_in[9];
    const float* W3  = (const float*)d_in[10];
    const float* b3  = (const float*)d_in[11];
    float* out = (float*)d_out;                 // [N, 64] fp32

    char* ws = (char*)d_ws;
    size_t off = 0;
    auto alloc = [&](size_t bytes) { char* p = ws + off; off += (bytes + 255) & ~(size_t)255; return p; };
    // contiguous zero region: stats1 | stats2 (zeroed in k_hist_wconv)
    float* stats1   = (float*)alloc(256 * 4);
    float* stats2   = (float*)alloc(256 * 4);
    unsigned int*  basesU = (unsigned int*)alloc((size_t)NCH * NW * 4);  // 800 KB
    unsigned char* rank8  = (unsigned char*)alloc((size_t)N_EDGES);     // 800 KB
    float* inv_sqrt = (float*)alloc((size_t)N_NODES * 4);
    int*   excl     = (int*)  alloc((size_t)N_NODES * 4);
    int*   partials = (int*)  alloc(256 * 4);
    int*   rowptr   = (int*)  alloc((size_t)(N_NODES + 1) * 4);
    int*   esrc     = (int*)  alloc((size_t)N_EDGES * 4);
    unsigned short* Wf1 = (unsigned short*)alloc((size_t)128 * 128 * 2);
    unsigned short* Wf2 = (unsigned short*)alloc((size_t)128 * 128 * 2);
    unsigned short* Wf3 = (unsigned short*)alloc((size_t)64 * 128 * 2);
    unsigned short* h1  = (unsigned short*)alloc((size_t)N_NODES * 128 * 2);
    unsigned short* h2  = (unsigned short*)alloc((size_t)N_NODES * 128 * 2);
    unsigned short* h3  = (unsigned short*)alloc((size_t)N_NODES * 64 * 2);
    unsigned short* agg1 = (unsigned short*)alloc((size_t)N_NODES * 128 * 2);
    unsigned short* agg2 = (unsigned short*)alloc((size_t)N_NODES * 128 * 2);

    // 1: LDS chunk histograms + rank bytes || weight packing + stats zero
    k_hist_wconv<<<NCH + WCONV_NB, 256, 0, stream>>>(ei, rank8, basesU,
                                                     W1, W2, W3, Wf1, Wf2, Wf3,
                                                     (int4*)stats1);
    // 2: layer-1 GEMM (MFMA pipe) || scan stage 1 (chunk-base fold + excl)
    k_gemm1_scan1<<<GEMM_NB + SCAN_NB, 256, 0, stream>>>(x, Wf1, h1, basesU,
                                                         inv_sqrt, excl, partials);
    // 3: scan2 apply -> rowptr || atomic-free CSR fill
    k_scan2_fill<<<SCAN_NB + FILL_NB, 256, 0, stream>>>(excl, partials, rowptr,
                                                        ei, rank8,
                                                        (const unsigned char*)basesU,
                                                        esrc);
    // 4-5: layer 1 aggregate + stats
    k_agg<128, true><<<N_NODES / 16, 256, 0, stream>>>(rowptr, esrc, inv_sqrt, h1, b1, agg1);
    k_stats<<<256, 256, 0, stream>>>(agg1, stats1);
    // 6-8: layer 2
    k_gemm_bn<128><<<GEMM_NB, 256, 0, stream>>>(agg1, Wf2, stats1, g1, bt1, h2);
    k_agg<128, true><<<N_NODES / 16, 256, 0, stream>>>(rowptr, esrc, inv_sqrt, h2, b2, agg2);
    k_stats<<<256, 256, 0, stream>>>(agg2, stats2);
    // 9-10: layer 3 (aggregate straight into d_out, fp32)
    k_gemm_bn<64><<<GEMM_NB, 256, 0, stream>>>(agg2, Wf3, stats2, g2, bt2, h3);
    k_agg<64, false><<<(N_NODES + 31) / 32, 256, 0, stream>>>(rowptr, esrc, inv_sqrt, h3, b3, out);
}

// Round 13
// 302.263 us; speedup vs baseline: 3.1315x; 1.0139x over previous
//
#include <hip/hip_runtime.h>

#define N_NODES 50000
#define N_EDGES 800000
static constexpr float EPS = 1e-5f;
static constexpr int NCH   = 16;                 // histogram chunks
static constexpr int EPC   = N_EDGES / NCH;      // 50000 edges per chunk
static constexpr int NW    = (N_NODES + 3) / 4;  // 12500 byte-packed words
static constexpr int SCAN_NB = (N_NODES + 1023) / 1024;   // 49 (4 nodes/thread)
static constexpr int GEMM_NB = (N_NODES + 127) / 128;     // 391 (128-row tiles)
static constexpr int FILL_NB = (N_EDGES + 1023) / 1024;   // 782 (4 edges/thread)
static constexpr int WCONV_NB = 160;

using bf16x8 = __attribute__((ext_vector_type(8))) short;  // 8 bf16 (4 VGPRs)
using f32x4  = __attribute__((ext_vector_type(4))) float;

// ---- bf16 helpers (raw-bit, RNE) ----
static __device__ __forceinline__ unsigned short f2bf(float f) {
    unsigned int u = __float_as_uint(f);
    return (unsigned short)((u + 0x7FFFu + ((u >> 16) & 1u)) >> 16);
}
static __device__ __forceinline__ float blo(unsigned int w) { return __uint_as_float(w << 16); }
static __device__ __forceinline__ float bhi(unsigned int w) { return __uint_as_float(w & 0xffff0000u); }

// ---------------------------------------------------------------------------
// fused: blocks [0,NCH) = per-chunk LDS byte-packed histogram + local rank
//        blocks [NCH,..) = W->bf16 fragment packing + stats zeroing
// ---------------------------------------------------------------------------
__global__ __launch_bounds__(256) void k_hist_wconv(
    const int* __restrict__ ei, unsigned char* __restrict__ rank8,
    unsigned int* __restrict__ basesU,
    const float* __restrict__ W1, const float* __restrict__ W2,
    const float* __restrict__ W3,
    unsigned short* __restrict__ Wf1, unsigned short* __restrict__ Wf2,
    unsigned short* __restrict__ Wf3, int4* __restrict__ statz) {
    __shared__ unsigned int h[NW];   // 50 KB
    const int t = threadIdx.x;
    if (blockIdx.x < NCH) {
        for (int i = t; i < NW; i += 256) h[i] = 0;
        __syncthreads();
        const int cbeg = blockIdx.x * EPC;
        for (int e0 = cbeg + t * 4; e0 < cbeg + EPC; e0 += 1024) {
            int4 d4 = *(const int4*)&ei[N_EDGES + e0];
            int sh0 = (d4.x & 3) * 8, sh1 = (d4.y & 3) * 8;
            int sh2 = (d4.z & 3) * 8, sh3 = (d4.w & 3) * 8;
            unsigned int o0 = atomicAdd(&h[d4.x >> 2], 1u << sh0);
            unsigned int o1 = atomicAdd(&h[d4.y >> 2], 1u << sh1);
            unsigned int o2 = atomicAdd(&h[d4.z >> 2], 1u << sh2);
            unsigned int o3 = atomicAdd(&h[d4.w >> 2], 1u << sh3);
            unsigned int pk = ((o0 >> sh0) & 0xffu) | (((o1 >> sh1) & 0xffu) << 8)
                            | (((o2 >> sh2) & 0xffu) << 16) | (((o3 >> sh3) & 0xffu) << 24);
            *(unsigned int*)&rank8[e0] = pk;
        }
        __syncthreads();
        for (int i = t; i < NW; i += 256)
            basesU[blockIdx.x * NW + i] = h[i];
    } else {
        int gid = (blockIdx.x - NCH) * 256 + t;   // < 40960
        if (gid < 128) statz[gid] = make_int4(0, 0, 0, 0);   // 2 KB stats region
        const float* W; unsigned short* Wf; int NCOL, idx;
        if (gid < 16384)      { W = W1; Wf = Wf1; NCOL = 128; idx = gid; }
        else if (gid < 32768) { W = W2; Wf = Wf2; NCOL = 128; idx = gid - 16384; }
        else                  { W = W3; Wf = Wf3; NCOL = 64;  idx = gid - 32768; }
        int j  = idx & 7;
        int l  = (idx >> 3) & 63;
        int s  = (idx >> 9) & 3;
        int tn = idx >> 11;
        int n = tn * 16 + (l & 15);
        int k = s * 32 + (l >> 4) * 8 + j;
        Wf[idx] = f2bf(W[k * NCOL + n]);
    }
}

// ---------------------------------------------------------------------------
// MFMA GEMM body, 128-row tile: H(bf16) = act(A) @ W, act = BN+ReLU if BN.
// Each wave owns rows [wv*32, wv*32+32) = two 16-row m-tiles, so every
// B-fragment load feeds 2 MFMAs. C is repacked through LDS (reusing As after
// A-fragments are in registers) and stored as coalesced uint4.
// ---------------------------------------------------------------------------
template <int NCOL, bool BN, bool ABF16>
static __device__ __forceinline__ void gemm_body(
    int row0, int t,
    const void* __restrict__ Ap, const unsigned short* __restrict__ Wf,
    const float* __restrict__ stats,
    const float* __restrict__ gamma, const float* __restrict__ beta,
    unsigned short* __restrict__ H,
    unsigned short* As, float* sc_s, float* sh_s) {
    if (BN) {
        if (t < 128) {
            float s  = stats[t];
            float sq = stats[128 + t];
            float mean = s * (1.0f / N_NODES);
            float var  = sq * (1.0f / N_NODES) - mean * mean;
            float sc = gamma[t] * rsqrtf(var + EPS);
            sc_s[t] = sc;
            sh_s[t] = beta[t] - mean * sc;
        }
        __syncthreads();
    }

    // ---- stage 128x128 A-tile into LDS as bf16 (BN+ReLU fused, fp32 math) ----
#pragma unroll
    for (int i = 0; i < 8; i++) {
        int q = i * 256 + t;          // 2048 groups of 8 elements
        int row = q >> 4;             // 0..127
        int c8  = (q & 15) * 8;
        int grow = row0 + row;
        float v[8];
        if (grow < N_NODES) {
            if (ABF16) {
                uint4 p = *(const uint4*)((const unsigned short*)Ap + (size_t)grow * 128 + c8);
                v[0] = blo(p.x); v[1] = bhi(p.x); v[2] = blo(p.y); v[3] = bhi(p.y);
                v[4] = blo(p.z); v[5] = bhi(p.z); v[6] = blo(p.w); v[7] = bhi(p.w);
            } else {
                const float* Af = (const float*)Ap + (size_t)grow * 128 + c8;
                float4 f0 = *(const float4*)Af;
                float4 f1 = *(const float4*)(Af + 4);
                v[0] = f0.x; v[1] = f0.y; v[2] = f0.z; v[3] = f0.w;
                v[4] = f1.x; v[5] = f1.y; v[6] = f1.z; v[7] = f1.w;
            }
        } else {
#pragma unroll
            for (int j = 0; j < 8; j++) v[j] = 0.f;
        }
        if (BN) {
#pragma unroll
            for (int j = 0; j < 8; j++)
                v[j] = fmaxf(fmaf(v[j], sc_s[c8 + j], sh_s[c8 + j]), 0.f);
        }
        uint4 pk;
        pk.x = (unsigned)f2bf(v[0]) | ((unsigned)f2bf(v[1]) << 16);
        pk.y = (unsigned)f2bf(v[2]) | ((unsigned)f2bf(v[3]) << 16);
        pk.z = (unsigned)f2bf(v[4]) | ((unsigned)f2bf(v[5]) << 16);
        pk.w = (unsigned)f2bf(v[6]) | ((unsigned)f2bf(v[7]) << 16);
        *(uint4*)&As[row * 136 + c8] = pk;
    }
    __syncthreads();

    // ---- A fragments (both m-tiles) into registers ----
    const int wv = t >> 6;
    const int l  = t & 63;
    const int m  = l & 15;
    const int kq = l >> 4;

    bf16x8 a0[4], a1[4];
    const unsigned short* ar0 = &As[(wv * 32 + m) * 136 + kq * 8];
    const unsigned short* ar1 = &As[(wv * 32 + 16 + m) * 136 + kq * 8];
#pragma unroll
    for (int s = 0; s < 4; s++) {
        a0[s] = *(const bf16x8*)(ar0 + s * 32);
        a1[s] = *(const bf16x8*)(ar1 + s * 32);
    }
    __syncthreads();   // all frags loaded; As becomes the C buffer

    // ---- MFMA: each B-fragment feeds 2 MFMAs; C -> LDS ----
    constexpr int NT = NCOL / 16;
#pragma unroll
    for (int tn = 0; tn < NT; tn++) {
        f32x4 c0 = {0.f, 0.f, 0.f, 0.f};
        f32x4 c1 = {0.f, 0.f, 0.f, 0.f};
#pragma unroll
        for (int s = 0; s < 4; s++) {
            bf16x8 b = *(const bf16x8*)&Wf[(size_t)((tn * 4 + s) * 64 + l) * 8];
            c0 = __builtin_amdgcn_mfma_f32_16x16x32_bf16(a0[s], b, c0, 0, 0, 0);
            c1 = __builtin_amdgcn_mfma_f32_16x16x32_bf16(a1[s], b, c1, 0, 0, 0);
        }
        int col = tn * 16 + m;
#pragma unroll
        for (int r = 0; r < 4; r++) {
            As[(wv * 32 + kq * 4 + r) * 136 + col]      = f2bf(c0[r]);
            As[(wv * 32 + 16 + kq * 4 + r) * 136 + col] = f2bf(c1[r]);
        }
    }
    __syncthreads();

    // ---- coalesced uint4 store of the C tile ----
    constexpr int GPR  = NCOL / 8;          // groups per row (16 or 8)
    constexpr int ITER = 128 * GPR / 256;   // 8 or 4
#pragma unroll
    for (int i = 0; i < ITER; i++) {
        int q = i * 256 + t;
        int row = q / GPR;
        int c8  = (q % GPR) * 8;
        int grow = row0 + row;
        if (grow < N_NODES) {
            uint4 pk = *(const uint4*)&As[row * 136 + c8];
            *(uint4*)&H[(size_t)grow * NCOL + c8] = pk;
        }
    }
    __syncthreads();   // protect As if body reused
}

// standalone GEMM kernels for layers 2/3
template <int NCOL>
__global__ __launch_bounds__(256) void k_gemm_bn(
    const unsigned short* __restrict__ A, const unsigned short* __restrict__ Wf,
    const float* __restrict__ stats,
    const float* __restrict__ gamma, const float* __restrict__ beta,
    unsigned short* __restrict__ H) {
    __shared__ unsigned short As[128 * 136];
    __shared__ float sc_s[128], sh_s[128];
    gemm_body<NCOL, true, true>(blockIdx.x * 128, threadIdx.x, A, Wf, stats,
                                gamma, beta, H, As, sc_s, sh_s);
}

// ---------------------------------------------------------------------------
// fused: blocks [0,GEMM_NB) = layer-1 GEMM (MFMA pipe);
//        blocks [GEMM_NB,+SCAN_NB) = scan stage 1 over chunk bases
// ---------------------------------------------------------------------------
__global__ __launch_bounds__(256) void k_gemm1_scan1(
    const float* __restrict__ x, const unsigned short* __restrict__ Wf1,
    unsigned short* __restrict__ h1,
    unsigned int* __restrict__ basesU, float* __restrict__ inv_sqrt,
    int* __restrict__ excl, int* __restrict__ partials) {
    __shared__ unsigned short As[128 * 136];
    __shared__ float sc_s[128], sh_s[128];
    const int t = threadIdx.x;
    if (blockIdx.x < GEMM_NB) {
        gemm_body<128, false, false>(blockIdx.x * 128, t, x, Wf1,
                                     nullptr, nullptr, nullptr, h1, As, sc_s, sh_s);
    } else {
        int* shi = (int*)As;                      // reuse LDS
        const int g = (blockIdx.x - GEMM_NB) * 256 + t;   // node group (4 nodes)
        int r0 = 0, r1 = 0, r2 = 0, r3 = 0;
        if (g < NW) {
#pragma unroll
            for (int c = 0; c < NCH; c++) {
                unsigned int w = basesU[c * NW + g];
                unsigned int pb = (unsigned)r0 | ((unsigned)r1 << 8)
                                | ((unsigned)r2 << 16) | ((unsigned)r3 << 24);
                basesU[c * NW + g] = pb;          // in-place exclusive chunk base
                r0 += w & 0xff; r1 += (w >> 8) & 0xff;
                r2 += (w >> 16) & 0xff; r3 += (w >> 24) & 0xff;
            }
        }
        int S = r0 + r1 + r2 + r3;
        shi[t] = S;
        __syncthreads();
        for (int off = 1; off < 256; off <<= 1) {
            int u = (t >= off) ? shi[t - off] : 0;
            __syncthreads();
            shi[t] += u;
            __syncthreads();
        }
        int base = shi[t] - S;                    // exclusive prefix of this thread
        if (g < NW) {
            int i0 = g * 4;
            *(int4*)&excl[i0] = make_int4(base, base + r0, base + r0 + r1,
                                          base + r0 + r1 + r2);
            *(float4*)&inv_sqrt[i0] = make_float4(
                rsqrtf((float)r0 + 1.0f), rsqrtf((float)r1 + 1.0f),
                rsqrtf((float)r2 + 1.0f), rsqrtf((float)r3 + 1.0f));
        }
        if (t == 255) partials[blockIdx.x - GEMM_NB] = shi[t];
    }
}

// ---------------------------------------------------------------------------
// fused scan2 apply + CSR fill
// ---------------------------------------------------------------------------
__global__ __launch_bounds__(256) void k_scan2_fill(
    const int* __restrict__ excl, const int* __restrict__ partials,
    int* __restrict__ rowptr,
    const int* __restrict__ ei, const unsigned char* __restrict__ rank8,
    const unsigned char* __restrict__ cb8,
    int* __restrict__ esrc) {
    const int t = threadIdx.x;
    __shared__ int sh[256];
    __shared__ int ps[256];
    int v = (t < SCAN_NB) ? partials[t] : 0;
    sh[t] = v;
    __syncthreads();
    for (int off = 1; off < 256; off <<= 1) {
        int u = (t >= off) ? sh[t - off] : 0;
        __syncthreads();
        sh[t] += u;
        __syncthreads();
    }
    ps[t] = sh[t] - v;
    __syncthreads();

    if (blockIdx.x < SCAN_NB) {
        int i0 = (blockIdx.x * 256 + t) * 4;
        if (i0 < N_NODES) {
            int4 e4 = *(const int4*)&excl[i0];
            int b = ps[blockIdx.x];
            *(int4*)&rowptr[i0] = make_int4(e4.x + b, e4.y + b, e4.z + b, e4.w + b);
        }
        if (blockIdx.x == 0 && t == 0) rowptr[N_NODES] = N_EDGES;
    } else {
        int e0 = ((blockIdx.x - SCAN_NB) * 256 + t) * 4;
        if (e0 < N_EDGES) {
            const int c = e0 / EPC;               // group never straddles chunks
            const unsigned char* cb = cb8 + (size_t)c * N_NODES;
            int4 s4 = *(const int4*)&ei[e0];
            int4 d4 = *(const int4*)&ei[N_EDGES + e0];
            unsigned int r4 = *(const unsigned int*)&rank8[e0];
            int p0 = excl[d4.x] + ps[d4.x >> 10] + cb[d4.x] + (r4 & 0xff);
            int p1 = excl[d4.y] + ps[d4.y >> 10] + cb[d4.y] + ((r4 >> 8) & 0xff);
            int p2 = excl[d4.z] + ps[d4.z >> 10] + cb[d4.z] + ((r4 >> 16) & 0xff);
            int p3 = excl[d4.w] + ps[d4.w >> 10] + cb[d4.w] + ((r4 >> 24) & 0xff);
            esrc[p0] = s4.x;
            esrc[p1] = s4.y;
            esrc[p2] = s4.z;
            esrc[p3] = s4.w;
        }
    }
}

// ---------------------------------------------------------------------------
// CSR gather-aggregate from bf16 H, fp32 accumulate, 8-wide edge unroll,
// 16 B/lane (uint4 = 8 bf16). coef = inv_sqrt[s] * inv_sqrt[node] on the fly.
// ---------------------------------------------------------------------------
template <int F, bool OUTBF>
__global__ __launch_bounds__(256) void k_agg(const int* __restrict__ rowptr,
                                             const int* __restrict__ esrc,
                                             const float* __restrict__ inv_sqrt,
                                             const unsigned short* __restrict__ H,
                                             const float* __restrict__ bias,
                                             void* __restrict__ OUT) {
    constexpr int LPN = F / 8;              // lanes per node (16 or 8), uint4 each
    constexpr int NPB = 256 / LPN;          // nodes per block (16 or 32)
    const int t = threadIdx.x;
    const int node = blockIdx.x * NPB + t / LPN;
    const int lane = t % LPN;
    if (node >= N_NODES) return;

    const uint4* __restrict__ Hv = (const uint4*)H;   // 8 bf16 per uint4
    const int beg = rowptr[node];
    const int end = rowptr[node + 1];
    const float rsn = inv_sqrt[node];

    float acc[8];
#pragma unroll
    for (int i = 0; i < 8; i++) acc[i] = 0.f;

#define ACC8(P, C)                                                     \
    acc[0] = fmaf(blo((P).x), (C), acc[0]);                            \
    acc[1] = fmaf(bhi((P).x), (C), acc[1]);                            \
    acc[2] = fmaf(blo((P).y), (C), acc[2]);                            \
    acc[3] = fmaf(bhi((P).y), (C), acc[3]);                            \
    acc[4] = fmaf(blo((P).z), (C), acc[4]);                            \
    acc[5] = fmaf(bhi((P).z), (C), acc[5]);                            \
    acc[6] = fmaf(blo((P).w), (C), acc[6]);                            \
    acc[7] = fmaf(bhi((P).w), (C), acc[7]);

    int j = beg;
    for (; j + 7 < end; j += 8) {
        int4 sa = *(const int4*)&esrc[j];
        int4 sb = *(const int4*)&esrc[j + 4];
        uint4 p0 = Hv[(size_t)sa.x * LPN + lane];
        uint4 p1 = Hv[(size_t)sa.y * LPN + lane];
        uint4 p2 = Hv[(size_t)sa.z * LPN + lane];
        uint4 p3 = Hv[(size_t)sa.w * LPN + lane];
        uint4 p4 = Hv[(size_t)sb.x * LPN + lane];
        uint4 p5 = Hv[(size_t)sb.y * LPN + lane];
        uint4 p6 = Hv[(size_t)sb.z * LPN + lane];
        uint4 p7 = Hv[(size_t)sb.w * LPN + lane];
        float c0 = inv_sqrt[sa.x] * rsn, c1 = inv_sqrt[sa.y] * rsn;
        float c2 = inv_sqrt[sa.z] * rsn, c3 = inv_sqrt[sa.w] * rsn;
        float c4 = inv_sqrt[sb.x] * rsn, c5 = inv_sqrt[sb.y] * rsn;
        float c6 = inv_sqrt[sb.z] * rsn, c7 = inv_sqrt[sb.w] * rsn;
        ACC8(p0, c0) ACC8(p1, c1) ACC8(p2, c2) ACC8(p3, c3)
        ACC8(p4, c4) ACC8(p5, c5) ACC8(p6, c6) ACC8(p7, c7)
    }
    if (j + 3 < end) {
        int4 sa = *(const int4*)&esrc[j];
        uint4 p0 = Hv[(size_t)sa.x * LPN + lane];
        uint4 p1 = Hv[(size_t)sa.y * LPN + lane];
        uint4 p2 = Hv[(size_t)sa.z * LPN + lane];
        uint4 p3 = Hv[(size_t)sa.w * LPN + lane];
        float c0 = inv_sqrt[sa.x] * rsn, c1 = inv_sqrt[sa.y] * rsn;
        float c2 = inv_sqrt[sa.z] * rsn, c3 = inv_sqrt[sa.w] * rsn;
        ACC8(p0, c0) ACC8(p1, c1) ACC8(p2, c2) ACC8(p3, c3)
        j += 4;
    }
    for (; j < end; j++) {
        int s0 = esrc[j];
        float c0 = inv_sqrt[s0] * rsn;
        uint4 p0 = Hv[(size_t)s0 * LPN + lane];
        ACC8(p0, c0)
    }
#undef ACC8

    // self-loop + bias (self coef = rsn^2)
    uint4 ps = Hv[(size_t)node * LPN + lane];
    float idv = rsn * rsn;
    float4 b0 = ((const float4*)bias)[lane * 2];
    float4 b1 = ((const float4*)bias)[lane * 2 + 1];
    acc[0] = fmaf(blo(ps.x), idv, acc[0]) + b0.x;
    acc[1] = fmaf(bhi(ps.x), idv, acc[1]) + b0.y;
    acc[2] = fmaf(blo(ps.y), idv, acc[2]) + b0.z;
    acc[3] = fmaf(bhi(ps.y), idv, acc[3]) + b0.w;
    acc[4] = fmaf(blo(ps.z), idv, acc[4]) + b1.x;
    acc[5] = fmaf(bhi(ps.z), idv, acc[5]) + b1.y;
    acc[6] = fmaf(blo(ps.w), idv, acc[6]) + b1.z;
    acc[7] = fmaf(bhi(ps.w), idv, acc[7]) + b1.w;

    if (OUTBF) {
        uint4 pk;
        pk.x = (unsigned)f2bf(acc[0]) | ((unsigned)f2bf(acc[1]) << 16);
        pk.y = (unsigned)f2bf(acc[2]) | ((unsigned)f2bf(acc[3]) << 16);
        pk.z = (unsigned)f2bf(acc[4]) | ((unsigned)f2bf(acc[5]) << 16);
        pk.w = (unsigned)f2bf(acc[6]) | ((unsigned)f2bf(acc[7]) << 16);
        ((uint4*)OUT)[(size_t)node * LPN + lane] = pk;
    } else {
        float4* o = (float4*)OUT + ((size_t)node * LPN + lane) * 2;
        o[0] = make_float4(acc[0], acc[1], acc[2], acc[3]);
        o[1] = make_float4(acc[4], acc[5], acc[6], acc[7]);
    }
}

// ---------------------------------------------------------------------------
// column stats over bf16 A[N,128]
// ---------------------------------------------------------------------------
__global__ __launch_bounds__(256) void k_stats(const unsigned short* __restrict__ A,
                                               float* __restrict__ stats) {
    const int t  = threadIdx.x;
    const int c4 = t & 31;
    const int rr = t >> 5;
    float4 sum = make_float4(0.f, 0.f, 0.f, 0.f);
    float4 sq  = make_float4(0.f, 0.f, 0.f, 0.f);
    for (int row = blockIdx.x * 8 + rr; row < N_NODES; row += gridDim.x * 8) {
        uint2 p = *(const uint2*)&A[(size_t)row * 128 + c4 * 4];
        float vx = blo(p.x), vy = bhi(p.x), vz = blo(p.y), vw = bhi(p.y);
        sum.x += vx; sum.y += vy; sum.z += vz; sum.w += vw;
        sq.x += vx * vx; sq.y += vy * vy; sq.z += vz * vz; sq.w += vw * vw;
    }
    __shared__ float4 red[2][8][32];
    red[0][rr][c4] = sum;
    red[1][rr][c4] = sq;
    __syncthreads();
    if (t < 32) {
        float4 s = make_float4(0.f, 0.f, 0.f, 0.f);
        float4 q = make_float4(0.f, 0.f, 0.f, 0.f);
#pragma unroll
        for (int i = 0; i < 8; i++) {
            float4 a = red[0][i][t];
            float4 b = red[1][i][t];
            s.x += a.x; s.y += a.y; s.z += a.z; s.w += a.w;
            q.x += b.x; q.y += b.y; q.z += b.z; q.w += b.w;
        }
        int c = t * 4;
        atomicAdd(&stats[c + 0], s.x); atomicAdd(&stats[c + 1], s.y);
        atomicAdd(&stats[c + 2], s.z); atomicAdd(&stats[c + 3], s.w);
        atomicAdd(&stats[128 + c + 0], q.x); atomicAdd(&stats[128 + c + 1], q.y);
        atomicAdd(&stats[128 + c + 2], q.z); atomicAdd(&stats[128 + c + 3], q.w);
    }
}

// ---------------------------------------------------------------------------
extern "C" void kernel_launch(void* const* d_in, const int* in_sizes, int n_in,
                              void* d_out, int out_size, void* d_ws, size_t ws_size,
                              hipStream_t stream) {
    const float* x   = (const float*)d_in[0];
    const int*   ei  = (const int*)d_in[1];
    const float* W1  = (const float*)d_in[2];
    const float* b1  = (const float*)d_in[3];
    const float* g1  = (const float*)d_in[4];
    const float* bt1 = (const float*)d_in[5];
    const float* W2  = (const float*)d_in[6];
    const float* b2  = (const float*)d_in[7];
    const float* g2  = (const float*)d_in[8];
    const float* bt2 = (const float*)d_in[9];
    const float* W3  = (const float*)d_in[10];
    const float* b3  = (const float*)d_in[11];
    float* out = (float*)d_out;                 // [N, 64] fp32

    char* ws = (char*)d_ws;
    size_t off = 0;
    auto alloc = [&](size_t bytes) { char* p = ws + off; off += (bytes + 255) & ~(size_t)255; return p; };
    // contiguous zero region: stats1 | stats2 (zeroed in k_hist_wconv)
    float* stats1   = (float*)alloc(256 * 4);
    float* stats2   = (float*)alloc(256 * 4);
    unsigned int*  basesU = (unsigned int*)alloc((size_t)NCH * NW * 4);  // 800 KB
    unsigned char* rank8  = (unsigned char*)alloc((size_t)N_EDGES);     // 800 KB
    float* inv_sqrt = (float*)alloc((size_t)N_NODES * 4);
    int*   excl     = (int*)  alloc((size_t)N_NODES * 4);
    int*   partials = (int*)  alloc(256 * 4);
    int*   rowptr   = (int*)  alloc((size_t)(N_NODES + 1) * 4);
    int*   esrc     = (int*)  alloc((size_t)N_EDGES * 4);
    unsigned short* Wf1 = (unsigned short*)alloc((size_t)128 * 128 * 2);
    unsigned short* Wf2 = (unsigned short*)alloc((size_t)128 * 128 * 2);
    unsigned short* Wf3 = (unsigned short*)alloc((size_t)64 * 128 * 2);
    unsigned short* h1  = (unsigned short*)alloc((size_t)N_NODES * 128 * 2);
    unsigned short* h2  = (unsigned short*)alloc((size_t)N_NODES * 128 * 2);
    unsigned short* h3  = (unsigned short*)alloc((size_t)N_NODES * 64 * 2);
    unsigned short* agg1 = (unsigned short*)alloc((size_t)N_NODES * 128 * 2);
    unsigned short* agg2 = (unsigned short*)alloc((size_t)N_NODES * 128 * 2);

    // 1: LDS chunk histograms + rank bytes || weight packing + stats zero
    k_hist_wconv<<<NCH + WCONV_NB, 256, 0, stream>>>(ei, rank8, basesU,
                                                     W1, W2, W3, Wf1, Wf2, Wf3,
                                                     (int4*)stats1);
    // 2: layer-1 GEMM (MFMA pipe) || scan stage 1 (chunk-base fold + excl)
    k_gemm1_scan1<<<GEMM_NB + SCAN_NB, 256, 0, stream>>>(x, Wf1, h1, basesU,
                                                         inv_sqrt, excl, partials);
    // 3: scan2 apply -> rowptr || atomic-free CSR fill
    k_scan2_fill<<<SCAN_NB + FILL_NB, 256, 0, stream>>>(excl, partials, rowptr,
                                                        ei, rank8,
                                                        (const unsigned char*)basesU,
                                                        esrc);
    // 4-5: layer 1 aggregate + stats
    k_agg<128, true><<<N_NODES / 16, 256, 0, stream>>>(rowptr, esrc, inv_sqrt, h1, b1, agg1);
    k_stats<<<256, 256, 0, stream>>>(agg1, stats1);
    // 6-8: layer 2
    k_gemm_bn<128><<<GEMM_NB, 256, 0, stream>>>(agg1, Wf2, stats1, g1, bt1, h2);
    k_agg<128, true><<<N_NODES / 16, 256, 0, stream>>>(rowptr, esrc, inv_sqrt, h2, b2, agg2);
    k_stats<<<256, 256, 0, stream>>>(agg2, stats2);
    // 9-10: layer 3 (aggregate straight into d_out, fp32)
    k_gemm_bn<64><<<GEMM_NB, 256, 0, stream>>>(agg2, Wf3, stats2, g2, bt2, h3);
    k_agg<64, false><<<(N_NODES + 31) / 32, 256, 0, stream>>>(rowptr, esrc, inv_sqrt, h3, b3, out);
}

// Round 14
// 257.979 us; speedup vs baseline: 3.6691x; 1.1717x over previous
//
#include <hip/hip_runtime.h>

#define N_NODES 50000
#define N_EDGES 800000
static constexpr float EPS = 1e-5f;
static constexpr int NCH   = 32;                 // histogram chunks
static constexpr int EPC   = N_EDGES / NCH;      // 25000 edges per chunk (4-aligned)
static constexpr int NW    = (N_NODES + 3) / 4;  // 12500 byte-packed words
static constexpr int SCAN_NB = (N_NODES + 1023) / 1024;   // 49 (4 nodes/thread)
static constexpr int GEMM_NB = (N_NODES + 127) / 128;     // 391 (128-row tiles)
static constexpr int FILL_NB = (N_EDGES + 1023) / 1024;   // 782 (4 edges/thread)
static constexpr int WCONV_NB = 160;

using bf16x8 = __attribute__((ext_vector_type(8))) short;  // 8 bf16 (4 VGPRs)
using f32x4  = __attribute__((ext_vector_type(4))) float;

// ---- bf16 helpers (raw-bit, RNE) ----
static __device__ __forceinline__ unsigned short f2bf(float f) {
    unsigned int u = __float_as_uint(f);
    return (unsigned short)((u + 0x7FFFu + ((u >> 16) & 1u)) >> 16);
}
static __device__ __forceinline__ float blo(unsigned int w) { return __uint_as_float(w << 16); }
static __device__ __forceinline__ float bhi(unsigned int w) { return __uint_as_float(w & 0xffff0000u); }

// ---------------------------------------------------------------------------
// fused: blocks [0,NCH) = per-chunk LDS byte-packed histogram + local rank
//        blocks [NCH,..) = W->bf16 fragment packing + stats zeroing
// ---------------------------------------------------------------------------
__global__ __launch_bounds__(256) void k_hist_wconv(
    const int* __restrict__ ei, unsigned char* __restrict__ rank8,
    unsigned int* __restrict__ hcnt,
    const float* __restrict__ W1, const float* __restrict__ W2,
    const float* __restrict__ W3,
    unsigned short* __restrict__ Wf1, unsigned short* __restrict__ Wf2,
    unsigned short* __restrict__ Wf3, int4* __restrict__ statz) {
    __shared__ unsigned int h[NW];   // 50 KB
    const int t = threadIdx.x;
    if (blockIdx.x < NCH) {
        for (int i = t; i < NW; i += 256) h[i] = 0;
        __syncthreads();
        const int cbeg = blockIdx.x * EPC;
        for (int e0 = cbeg + t * 4; e0 < cbeg + EPC; e0 += 1024) {
            int4 d4 = *(const int4*)&ei[N_EDGES + e0];
            int sh0 = (d4.x & 3) * 8, sh1 = (d4.y & 3) * 8;
            int sh2 = (d4.z & 3) * 8, sh3 = (d4.w & 3) * 8;
            unsigned int o0 = atomicAdd(&h[d4.x >> 2], 1u << sh0);
            unsigned int o1 = atomicAdd(&h[d4.y >> 2], 1u << sh1);
            unsigned int o2 = atomicAdd(&h[d4.z >> 2], 1u << sh2);
            unsigned int o3 = atomicAdd(&h[d4.w >> 2], 1u << sh3);
            unsigned int pk = ((o0 >> sh0) & 0xffu) | (((o1 >> sh1) & 0xffu) << 8)
                            | (((o2 >> sh2) & 0xffu) << 16) | (((o3 >> sh3) & 0xffu) << 24);
            *(unsigned int*)&rank8[e0] = pk;
        }
        __syncthreads();
        for (int i = t; i < NW; i += 256)
            hcnt[blockIdx.x * NW + i] = h[i];
    } else {
        int gid = (blockIdx.x - NCH) * 256 + t;   // < 40960
        if (gid < 128) statz[gid] = make_int4(0, 0, 0, 0);   // 2 KB stats region
        const float* W; unsigned short* Wf; int NCOL, idx;
        if (gid < 16384)      { W = W1; Wf = Wf1; NCOL = 128; idx = gid; }
        else if (gid < 32768) { W = W2; Wf = Wf2; NCOL = 128; idx = gid - 16384; }
        else                  { W = W3; Wf = Wf3; NCOL = 64;  idx = gid - 32768; }
        int j  = idx & 7;
        int l  = (idx >> 3) & 63;
        int s  = (idx >> 9) & 3;
        int tn = idx >> 11;
        int n = tn * 16 + (l & 15);
        int k = s * 32 + (l >> 4) * 8 + j;
        Wf[idx] = f2bf(W[k * NCOL + n]);
    }
}

// ---------------------------------------------------------------------------
// MFMA GEMM body, 128-row tile (see R13 notes): every B-fragment feeds 2
// MFMAs; C repacked through LDS and stored as coalesced uint4.
// ---------------------------------------------------------------------------
template <int NCOL, bool BN, bool ABF16>
static __device__ __forceinline__ void gemm_body(
    int row0, int t,
    const void* __restrict__ Ap, const unsigned short* __restrict__ Wf,
    const float* __restrict__ stats,
    const float* __restrict__ gamma, const float* __restrict__ beta,
    unsigned short* __restrict__ H,
    unsigned short* As, float* sc_s, float* sh_s) {
    if (BN) {
        if (t < 128) {
            float s  = stats[t];
            float sq = stats[128 + t];
            float mean = s * (1.0f / N_NODES);
            float var  = sq * (1.0f / N_NODES) - mean * mean;
            float sc = gamma[t] * rsqrtf(var + EPS);
            sc_s[t] = sc;
            sh_s[t] = beta[t] - mean * sc;
        }
        __syncthreads();
    }

#pragma unroll
    for (int i = 0; i < 8; i++) {
        int q = i * 256 + t;          // 2048 groups of 8 elements
        int row = q >> 4;             // 0..127
        int c8  = (q & 15) * 8;
        int grow = row0 + row;
        float v[8];
        if (grow < N_NODES) {
            if (ABF16) {
                uint4 p = *(const uint4*)((const unsigned short*)Ap + (size_t)grow * 128 + c8);
                v[0] = blo(p.x); v[1] = bhi(p.x); v[2] = blo(p.y); v[3] = bhi(p.y);
                v[4] = blo(p.z); v[5] = bhi(p.z); v[6] = blo(p.w); v[7] = bhi(p.w);
            } else {
                const float* Af = (const float*)Ap + (size_t)grow * 128 + c8;
                float4 f0 = *(const float4*)Af;
                float4 f1 = *(const float4*)(Af + 4);
                v[0] = f0.x; v[1] = f0.y; v[2] = f0.z; v[3] = f0.w;
                v[4] = f1.x; v[5] = f1.y; v[6] = f1.z; v[7] = f1.w;
            }
        } else {
#pragma unroll
            for (int j = 0; j < 8; j++) v[j] = 0.f;
        }
        if (BN) {
#pragma unroll
            for (int j = 0; j < 8; j++)
                v[j] = fmaxf(fmaf(v[j], sc_s[c8 + j], sh_s[c8 + j]), 0.f);
        }
        uint4 pk;
        pk.x = (unsigned)f2bf(v[0]) | ((unsigned)f2bf(v[1]) << 16);
        pk.y = (unsigned)f2bf(v[2]) | ((unsigned)f2bf(v[3]) << 16);
        pk.z = (unsigned)f2bf(v[4]) | ((unsigned)f2bf(v[5]) << 16);
        pk.w = (unsigned)f2bf(v[6]) | ((unsigned)f2bf(v[7]) << 16);
        *(uint4*)&As[row * 136 + c8] = pk;
    }
    __syncthreads();

    const int wv = t >> 6;
    const int l  = t & 63;
    const int m  = l & 15;
    const int kq = l >> 4;

    bf16x8 a0[4], a1[4];
    const unsigned short* ar0 = &As[(wv * 32 + m) * 136 + kq * 8];
    const unsigned short* ar1 = &As[(wv * 32 + 16 + m) * 136 + kq * 8];
#pragma unroll
    for (int s = 0; s < 4; s++) {
        a0[s] = *(const bf16x8*)(ar0 + s * 32);
        a1[s] = *(const bf16x8*)(ar1 + s * 32);
    }
    __syncthreads();   // all frags loaded; As becomes the C buffer

    constexpr int NT = NCOL / 16;
#pragma unroll
    for (int tn = 0; tn < NT; tn++) {
        f32x4 c0 = {0.f, 0.f, 0.f, 0.f};
        f32x4 c1 = {0.f, 0.f, 0.f, 0.f};
#pragma unroll
        for (int s = 0; s < 4; s++) {
            bf16x8 b = *(const bf16x8*)&Wf[(size_t)((tn * 4 + s) * 64 + l) * 8];
            c0 = __builtin_amdgcn_mfma_f32_16x16x32_bf16(a0[s], b, c0, 0, 0, 0);
            c1 = __builtin_amdgcn_mfma_f32_16x16x32_bf16(a1[s], b, c1, 0, 0, 0);
        }
        int col = tn * 16 + m;
#pragma unroll
        for (int r = 0; r < 4; r++) {
            As[(wv * 32 + kq * 4 + r) * 136 + col]      = f2bf(c0[r]);
            As[(wv * 32 + 16 + kq * 4 + r) * 136 + col] = f2bf(c1[r]);
        }
    }
    __syncthreads();

    constexpr int GPR  = NCOL / 8;          // groups per row (16 or 8)
    constexpr int ITER = 128 * GPR / 256;   // 8 or 4
#pragma unroll
    for (int i = 0; i < ITER; i++) {
        int q = i * 256 + t;
        int row = q / GPR;
        int c8  = (q % GPR) * 8;
        int grow = row0 + row;
        if (grow < N_NODES) {
            uint4 pk = *(const uint4*)&As[row * 136 + c8];
            *(uint4*)&H[(size_t)grow * NCOL + c8] = pk;
        }
    }
    __syncthreads();
}

// standalone GEMM kernels for layers 2/3
template <int NCOL>
__global__ __launch_bounds__(256) void k_gemm_bn(
    const unsigned short* __restrict__ A, const unsigned short* __restrict__ Wf,
    const float* __restrict__ stats,
    const float* __restrict__ gamma, const float* __restrict__ beta,
    unsigned short* __restrict__ H) {
    __shared__ unsigned short As[128 * 136];
    __shared__ float sc_s[128], sh_s[128];
    gemm_body<NCOL, true, true>(blockIdx.x * 128, threadIdx.x, A, Wf, stats,
                                gamma, beta, H, As, sc_s, sh_s);
}

// ---------------------------------------------------------------------------
// fused: blocks [0,GEMM_NB) = layer-1 GEMM (MFMA pipe);
//        blocks [GEMM_NB,+SCAN_NB) = scan stage 1:
//          per node: total over NCH chunk counts; writes int cbase32[c][node]
//          = excl_local(node) + chunk_base(c,node)  (fill needs ONE gather);
//          block scan of totals -> excl + partials; inv_sqrt.
// ---------------------------------------------------------------------------
__global__ __launch_bounds__(256) void k_gemm1_scan1(
    const float* __restrict__ x, const unsigned short* __restrict__ Wf1,
    unsigned short* __restrict__ h1,
    const unsigned int* __restrict__ hcnt, int* __restrict__ cbase32,
    float* __restrict__ inv_sqrt,
    int* __restrict__ excl, int* __restrict__ partials) {
    __shared__ unsigned short As[128 * 136];
    __shared__ float sc_s[128], sh_s[128];
    const int t = threadIdx.x;
    if (blockIdx.x < GEMM_NB) {
        gemm_body<128, false, false>(blockIdx.x * 128, t, x, Wf1,
                                     nullptr, nullptr, nullptr, h1, As, sc_s, sh_s);
    } else {
        int* shi = (int*)As;                      // reuse LDS
        const int g = (blockIdx.x - GEMM_NB) * 256 + t;   // node group (4 nodes)
        int r0 = 0, r1 = 0, r2 = 0, r3 = 0;
        unsigned int cnt[NCH];
        if (g < NW) {
#pragma unroll
            for (int c = 0; c < NCH; c++) cnt[c] = hcnt[c * NW + g];
#pragma unroll
            for (int c = 0; c < NCH; c++) {
                unsigned int w = cnt[c];
                cnt[c] = (unsigned)r0 | ((unsigned)r1 << 8)
                       | ((unsigned)r2 << 16) | ((unsigned)r3 << 24);  // chunk base
                r0 += w & 0xff; r1 += (w >> 8) & 0xff;
                r2 += (w >> 16) & 0xff; r3 += (w >> 24) & 0xff;
            }
        }
        int S = r0 + r1 + r2 + r3;
        shi[t] = S;
        __syncthreads();
        for (int off = 1; off < 256; off <<= 1) {
            int u = (t >= off) ? shi[t - off] : 0;
            __syncthreads();
            shi[t] += u;
            __syncthreads();
        }
        int base = shi[t] - S;                    // block-local exclusive prefix
        if (g < NW) {
            int i0 = g * 4;
            int e0 = base, e1 = base + r0, e2 = base + r0 + r1, e3 = base + r0 + r1 + r2;
            *(int4*)&excl[i0] = make_int4(e0, e1, e2, e3);
            *(float4*)&inv_sqrt[i0] = make_float4(
                rsqrtf((float)r0 + 1.0f), rsqrtf((float)r1 + 1.0f),
                rsqrtf((float)r2 + 1.0f), rsqrtf((float)r3 + 1.0f));
            // cbase32[c][node] = excl_local + chunk base (int, fill = 1 gather)
#pragma unroll
            for (int c = 0; c < NCH; c++) {
                unsigned int pb = cnt[c];
                *(int4*)&cbase32[c * N_NODES + i0] = make_int4(
                    e0 + (int)(pb & 0xff), e1 + (int)((pb >> 8) & 0xff),
                    e2 + (int)((pb >> 16) & 0xff), e3 + (int)((pb >> 24) & 0xff));
            }
        }
        if (t == 255) partials[blockIdx.x - GEMM_NB] = shi[t];
    }
}

// ---------------------------------------------------------------------------
// fused scan2 apply + CSR fill:
// every block scans the 49 partials in LDS;
// blocks [0,SCAN_NB): rowptr[i] = excl[i] + ps[i>>10]
// blocks [SCAN_NB,+FILL_NB): pos = cbase32[c][d] + ps[d>>10] + rank8[e]
// ---------------------------------------------------------------------------
__global__ __launch_bounds__(256) void k_scan2_fill(
    const int* __restrict__ excl, const int* __restrict__ partials,
    int* __restrict__ rowptr,
    const int* __restrict__ ei, const unsigned char* __restrict__ rank8,
    const int* __restrict__ cbase32,
    int* __restrict__ esrc) {
    const int t = threadIdx.x;
    __shared__ int sh[256];
    __shared__ int ps[256];
    int v = (t < SCAN_NB) ? partials[t] : 0;
    sh[t] = v;
    __syncthreads();
    for (int off = 1; off < 256; off <<= 1) {
        int u = (t >= off) ? sh[t - off] : 0;
        __syncthreads();
        sh[t] += u;
        __syncthreads();
    }
    ps[t] = sh[t] - v;
    __syncthreads();

    if (blockIdx.x < SCAN_NB) {
        int i0 = (blockIdx.x * 256 + t) * 4;
        if (i0 < N_NODES) {
            int4 e4 = *(const int4*)&excl[i0];
            int b = ps[blockIdx.x];
            *(int4*)&rowptr[i0] = make_int4(e4.x + b, e4.y + b, e4.z + b, e4.w + b);
        }
        if (blockIdx.x == 0 && t == 0) rowptr[N_NODES] = N_EDGES;
    } else {
        int e0 = ((blockIdx.x - SCAN_NB) * 256 + t) * 4;
        if (e0 < N_EDGES) {
            const int* cb = cbase32 + (e0 / EPC) * N_NODES;  // group never straddles
            int4 s4 = *(const int4*)&ei[e0];
            int4 d4 = *(const int4*)&ei[N_EDGES + e0];
            unsigned int r4 = *(const unsigned int*)&rank8[e0];
            int p0 = cb[d4.x] + ps[d4.x >> 10] + (r4 & 0xff);
            int p1 = cb[d4.y] + ps[d4.y >> 10] + ((r4 >> 8) & 0xff);
            int p2 = cb[d4.z] + ps[d4.z >> 10] + ((r4 >> 16) & 0xff);
            int p3 = cb[d4.w] + ps[d4.w >> 10] + ((r4 >> 24) & 0xff);
            esrc[p0] = s4.x;
            esrc[p1] = s4.y;
            esrc[p2] = s4.z;
            esrc[p3] = s4.w;
        }
    }
}

// ---------------------------------------------------------------------------
// CSR gather-aggregate from bf16 H, fp32 accumulate, 8-wide edge unroll,
// 16 B/lane (uint4 = 8 bf16). coef = inv_sqrt[s] * inv_sqrt[node] on the fly.
// ---------------------------------------------------------------------------
template <int F, bool OUTBF>
__global__ __launch_bounds__(256) void k_agg(const int* __restrict__ rowptr,
                                             const int* __restrict__ esrc,
                                             const float* __restrict__ inv_sqrt,
                                             const unsigned short* __restrict__ H,
                                             const float* __restrict__ bias,
                                             void* __restrict__ OUT) {
    constexpr int LPN = F / 8;              // lanes per node (16 or 8), uint4 each
    constexpr int NPB = 256 / LPN;          // nodes per block (16 or 32)
    const int t = threadIdx.x;
    const int node = blockIdx.x * NPB + t / LPN;
    const int lane = t % LPN;
    if (node >= N_NODES) return;

    const uint4* __restrict__ Hv = (const uint4*)H;   // 8 bf16 per uint4
    const int beg = rowptr[node];
    const int end = rowptr[node + 1];
    const float rsn = inv_sqrt[node];

    float acc[8];
#pragma unroll
    for (int i = 0; i < 8; i++) acc[i] = 0.f;

#define ACC8(P, C)                                                     \
    acc[0] = fmaf(blo((P).x), (C), acc[0]);                            \
    acc[1] = fmaf(bhi((P).x), (C), acc[1]);                            \
    acc[2] = fmaf(blo((P).y), (C), acc[2]);                            \
    acc[3] = fmaf(bhi((P).y), (C), acc[3]);                            \
    acc[4] = fmaf(blo((P).z), (C), acc[4]);                            \
    acc[5] = fmaf(bhi((P).z), (C), acc[5]);                            \
    acc[6] = fmaf(blo((P).w), (C), acc[6]);                            \
    acc[7] = fmaf(bhi((P).w), (C), acc[7]);

    int j = beg;
    for (; j + 7 < end; j += 8) {
        int4 sa = *(const int4*)&esrc[j];
        int4 sb = *(const int4*)&esrc[j + 4];
        uint4 p0 = Hv[(size_t)sa.x * LPN + lane];
        uint4 p1 = Hv[(size_t)sa.y * LPN + lane];
        uint4 p2 = Hv[(size_t)sa.z * LPN + lane];
        uint4 p3 = Hv[(size_t)sa.w * LPN + lane];
        uint4 p4 = Hv[(size_t)sb.x * LPN + lane];
        uint4 p5 = Hv[(size_t)sb.y * LPN + lane];
        uint4 p6 = Hv[(size_t)sb.z * LPN + lane];
        uint4 p7 = Hv[(size_t)sb.w * LPN + lane];
        float c0 = inv_sqrt[sa.x] * rsn, c1 = inv_sqrt[sa.y] * rsn;
        float c2 = inv_sqrt[sa.z] * rsn, c3 = inv_sqrt[sa.w] * rsn;
        float c4 = inv_sqrt[sb.x] * rsn, c5 = inv_sqrt[sb.y] * rsn;
        float c6 = inv_sqrt[sb.z] * rsn, c7 = inv_sqrt[sb.w] * rsn;
        ACC8(p0, c0) ACC8(p1, c1) ACC8(p2, c2) ACC8(p3, c3)
        ACC8(p4, c4) ACC8(p5, c5) ACC8(p6, c6) ACC8(p7, c7)
    }
    if (j + 3 < end) {
        int4 sa = *(const int4*)&esrc[j];
        uint4 p0 = Hv[(size_t)sa.x * LPN + lane];
        uint4 p1 = Hv[(size_t)sa.y * LPN + lane];
        uint4 p2 = Hv[(size_t)sa.z * LPN + lane];
        uint4 p3 = Hv[(size_t)sa.w * LPN + lane];
        float c0 = inv_sqrt[sa.x] * rsn, c1 = inv_sqrt[sa.y] * rsn;
        float c2 = inv_sqrt[sa.z] * rsn, c3 = inv_sqrt[sa.w] * rsn;
        ACC8(p0, c0) ACC8(p1, c1) ACC8(p2, c2) ACC8(p3, c3)
        j += 4;
    }
    for (; j < end; j++) {
        int s0 = esrc[j];
        float c0 = inv_sqrt[s0] * rsn;
        uint4 p0 = Hv[(size_t)s0 * LPN + lane];
        ACC8(p0, c0)
    }
#undef ACC8

    // self-loop + bias (self coef = rsn^2)
    uint4 ps = Hv[(size_t)node * LPN + lane];
    float idv = rsn * rsn;
    float4 b0 = ((const float4*)bias)[lane * 2];
    float4 b1 = ((const float4*)bias)[lane * 2 + 1];
    acc[0] = fmaf(blo(ps.x), idv, acc[0]) + b0.x;
    acc[1] = fmaf(bhi(ps.x), idv, acc[1]) + b0.y;
    acc[2] = fmaf(blo(ps.y), idv, acc[2]) + b0.z;
    acc[3] = fmaf(bhi(ps.y), idv, acc[3]) + b0.w;
    acc[4] = fmaf(blo(ps.z), idv, acc[4]) + b1.x;
    acc[5] = fmaf(bhi(ps.z), idv, acc[5]) + b1.y;
    acc[6] = fmaf(blo(ps.w), idv, acc[6]) + b1.z;
    acc[7] = fmaf(bhi(ps.w), idv, acc[7]) + b1.w;

    if (OUTBF) {
        uint4 pk;
        pk.x = (unsigned)f2bf(acc[0]) | ((unsigned)f2bf(acc[1]) << 16);
        pk.y = (unsigned)f2bf(acc[2]) | ((unsigned)f2bf(acc[3]) << 16);
        pk.z = (unsigned)f2bf(acc[4]) | ((unsigned)f2bf(acc[5]) << 16);
        pk.w = (unsigned)f2bf(acc[6]) | ((unsigned)f2bf(acc[7]) << 16);
        ((uint4*)OUT)[(size_t)node * LPN + lane] = pk;
    } else {
        float4* o = (float4*)OUT + ((size_t)node * LPN + lane) * 2;
        o[0] = make_float4(acc[0], acc[1], acc[2], acc[3]);
        o[1] = make_float4(acc[4], acc[5], acc[6], acc[7]);
    }
}

// ---------------------------------------------------------------------------
// column stats over bf16 A[N,128] (uint4 loads: 8 cols/lane)
// ---------------------------------------------------------------------------
__global__ __launch_bounds__(256) void k_stats(const unsigned short* __restrict__ A,
                                               float* __restrict__ stats) {
    const int t  = threadIdx.x;
    const int c8 = t & 15;    // 8-col group
    const int rr = t >> 4;    // 0..15
    float sum[8] = {0,0,0,0,0,0,0,0};
    float sq[8]  = {0,0,0,0,0,0,0,0};
    for (int row = blockIdx.x * 16 + rr; row < N_NODES; row += gridDim.x * 16) {
        uint4 p = *(const uint4*)&A[(size_t)row * 128 + c8 * 8];
        float v[8] = {blo(p.x), bhi(p.x), blo(p.y), bhi(p.y),
                      blo(p.z), bhi(p.z), blo(p.w), bhi(p.w)};
#pragma unroll
        for (int i = 0; i < 8; i++) { sum[i] += v[i]; sq[i] += v[i] * v[i]; }
    }
    __shared__ float red[16][16][8];   // 8 KB, reused twice
    // sums
#pragma unroll
    for (int i = 0; i < 8; i++) red[rr][c8][i] = sum[i];
    __syncthreads();
    if (t < 128) {      // t = c8*8+i over 16 groups? simpler: lane t<128 reduces col t
        int g = t >> 3, i = t & 7;
        float s = 0.f;
#pragma unroll
        for (int r = 0; r < 16; r++) s += red[r][g][i];
        atomicAdd(&stats[g * 8 + i], s);
    }
    __syncthreads();
#pragma unroll
    for (int i = 0; i < 8; i++) red[rr][c8][i] = sq[i];
    __syncthreads();
    if (t < 128) {
        int g = t >> 3, i = t & 7;
        float s = 0.f;
#pragma unroll
        for (int r = 0; r < 16; r++) s += red[r][g][i];
        atomicAdd(&stats[128 + g * 8 + i], s);
    }
}

// ---------------------------------------------------------------------------
extern "C" void kernel_launch(void* const* d_in, const int* in_sizes, int n_in,
                              void* d_out, int out_size, void* d_ws, size_t ws_size,
                              hipStream_t stream) {
    const float* x   = (const float*)d_in[0];
    const int*   ei  = (const int*)d_in[1];
    const float* W1  = (const float*)d_in[2];
    const float* b1  = (const float*)d_in[3];
    const float* g1  = (const float*)d_in[4];
    const float* bt1 = (const float*)d_in[5];
    const float* W2  = (const float*)d_in[6];
    const float* b2  = (const float*)d_in[7];
    const float* g2  = (const float*)d_in[8];
    const float* bt2 = (const float*)d_in[9];
    const float* W3  = (const float*)d_in[10];
    const float* b3  = (const float*)d_in[11];
    float* out = (float*)d_out;                 // [N, 64] fp32

    char* ws = (char*)d_ws;
    size_t off = 0;
    auto alloc = [&](size_t bytes) { char* p = ws + off; off += (bytes + 255) & ~(size_t)255; return p; };
    // contiguous zero region: stats1 | stats2 (zeroed in k_hist_wconv)
    float* stats1   = (float*)alloc(256 * 4);
    float* stats2   = (float*)alloc(256 * 4);
    unsigned int* hcnt   = (unsigned int*)alloc((size_t)NCH * NW * 4);   // 1.6 MB
    int*          cbase32 = (int*)alloc((size_t)NCH * N_NODES * 4);     // 6.4 MB
    unsigned char* rank8  = (unsigned char*)alloc((size_t)N_EDGES);     // 800 KB
    float* inv_sqrt = (float*)alloc((size_t)N_NODES * 4);
    int*   excl     = (int*)  alloc((size_t)N_NODES * 4);
    int*   partials = (int*)  alloc(256 * 4);
    int*   rowptr   = (int*)  alloc((size_t)(N_NODES + 1) * 4);
    int*   esrc     = (int*)  alloc((size_t)N_EDGES * 4);
    unsigned short* Wf1 = (unsigned short*)alloc((size_t)128 * 128 * 2);
    unsigned short* Wf2 = (unsigned short*)alloc((size_t)128 * 128 * 2);
    unsigned short* Wf3 = (unsigned short*)alloc((size_t)64 * 128 * 2);
    unsigned short* h1  = (unsigned short*)alloc((size_t)N_NODES * 128 * 2);
    unsigned short* h2  = (unsigned short*)alloc((size_t)N_NODES * 128 * 2);
    unsigned short* h3  = (unsigned short*)alloc((size_t)N_NODES * 64 * 2);
    unsigned short* agg1 = (unsigned short*)alloc((size_t)N_NODES * 128 * 2);
    unsigned short* agg2 = (unsigned short*)alloc((size_t)N_NODES * 128 * 2);

    // 1: LDS chunk histograms + rank bytes || weight packing + stats zero
    k_hist_wconv<<<NCH + WCONV_NB, 256, 0, stream>>>(ei, rank8, hcnt,
                                                     W1, W2, W3, Wf1, Wf2, Wf3,
                                                     (int4*)stats1);
    // 2: layer-1 GEMM (MFMA pipe) || scan1 (fold excl into chunk bases)
    k_gemm1_scan1<<<GEMM_NB + SCAN_NB, 256, 0, stream>>>(x, Wf1, h1, hcnt,
                                                         cbase32, inv_sqrt,
                                                         excl, partials);
    // 3: scan2 apply -> rowptr || atomic-free CSR fill (1 gather/edge)
    k_scan2_fill<<<SCAN_NB + FILL_NB, 256, 0, stream>>>(excl, partials, rowptr,
                                                        ei, rank8, cbase32, esrc);
    // 4-5: layer 1 aggregate + stats
    k_agg<128, true><<<N_NODES / 16, 256, 0, stream>>>(rowptr, esrc, inv_sqrt, h1, b1, agg1);
    k_stats<<<256, 256, 0, stream>>>(agg1, stats1);
    // 6-8: layer 2
    k_gemm_bn<128><<<GEMM_NB, 256, 0, stream>>>(agg1, Wf2, stats1, g1, bt1, h2);
    k_agg<128, true><<<N_NODES / 16, 256, 0, stream>>>(rowptr, esrc, inv_sqrt, h2, b2, agg2);
    k_stats<<<256, 256, 0, stream>>>(agg2, stats2);
    // 9-10: layer 3 (aggregate straight into d_out, fp32)
    k_gemm_bn<64><<<GEMM_NB, 256, 0, stream>>>(agg2, Wf3, stats2, g2, bt2, h3);
    k_agg<64, false><<<(N_NODES + 31) / 32, 256, 0, stream>>>(rowptr, esrc, inv_sqrt, h3, b3, out);
}